// Round 1
// baseline (335.557 us; speedup 1.0000x reference)
//
#include <hip/hip_runtime.h>
#include <math.h>

#define NEG_SLOPE 0.2f
#define LOG2E 1.4426950408889634f

typedef __attribute__((ext_vector_type(2))) _Float16 h2;
typedef __attribute__((ext_vector_type(4))) _Float16 h4;
typedef __attribute__((ext_vector_type(8))) _Float16 f16x8;
typedef __attribute__((ext_vector_type(4))) float f32x4;

typedef const __attribute__((address_space(1))) unsigned int* gu32p;
typedef __attribute__((address_space(3))) unsigned int* lu32p;

#define GLD16(g, l) __builtin_amdgcn_global_load_lds((gu32p)(g), (lu32p)(l), 16, 0, 0)

template<int CTRL>
__device__ __forceinline__ float dpp_add_f32(float x) {
    int y = __builtin_amdgcn_update_dpp(0, __float_as_int(x), CTRL, 0xF, 0xF, true);
    return x + __int_as_float(y);
}
__device__ __forceinline__ float rowsum16(float x) {
    x = dpp_add_f32<0xB1>(x);
    x = dpp_add_f32<0x4E>(x);
    x = dpp_add_f32<0x124>(x);
    x = dpp_add_f32<0x128>(x);
    return x;
}

// ---------------- CSR build ----------------

__global__ __launch_bounds__(256) void k_scan_block(const int* __restrict__ cnt,
                                                    int* __restrict__ out,
                                                    int* __restrict__ bsums, int n) {
    __shared__ int tmp[256];
    int t = threadIdx.x;
    int i = blockIdx.x * 256 + t;
    int v = (i < n) ? cnt[i] : 0;
    tmp[t] = v;
    __syncthreads();
    for (int d = 1; d < 256; d <<= 1) {
        int add = (t >= d) ? tmp[t - d] : 0;
        __syncthreads();
        tmp[t] += add;
        __syncthreads();
    }
    if (i < n) out[i] = tmp[t] - v;
    if (t == 255) bsums[blockIdx.x] = tmp[t];
}

__global__ __launch_bounds__(256) void k_scan_bsums(int* bsums, int nb) {
    __shared__ int tmp[256];
    int t = threadIdx.x;
    int v = (t < nb) ? bsums[t] : 0;
    tmp[t] = v;
    __syncthreads();
    for (int d = 1; d < 256; d <<= 1) {
        int add = (t >= d) ? tmp[t - d] : 0;
        __syncthreads();
        tmp[t] += add;
        __syncthreads();
    }
    if (t < nb) bsums[t] = tmp[t] - v;
}

__global__ __launch_bounds__(256) void k_scan_add(int* __restrict__ out,
                                                  const int* __restrict__ bsums,
                                                  int* __restrict__ cursor,
                                                  int n, int total) {
    int i = blockIdx.x * 256 + threadIdx.x;
    if (i < n) {
        int v = out[i] + bsums[blockIdx.x];
        out[i] = v;
        cursor[i] = v;
    }
    if (i == 0) out[n] = total;
}

__global__ __launch_bounds__(256) void k_scatter(const int* __restrict__ ei, int E, int Et,
                                                 int* __restrict__ cursor,
                                                 int* __restrict__ src_sorted) {
    int e = blockIdx.x * 256 + threadIdx.x;
    if (e < Et) {
        int s, d;
        if (e < E) { s = ei[e]; d = ei[E + e]; } else { s = d = e - E; }
        int pos = atomicAdd(&cursor[d], 1);
        src_sorted[pos] = s;
    }
}

// ---------------- fused prep: edge count + x cast + all weight casts ----------------

__global__ __launch_bounds__(256) void k_prep(
        const int* __restrict__ ei, int E, int Et, int* __restrict__ cnt,
        const float* __restrict__ x, _Float16* __restrict__ xb, int N, int F,
        const float* __restrict__ Wl1, const float* __restrict__ Wr1,
        const float* __restrict__ Wl2, const float* __restrict__ Wr2,
        const float* __restrict__ Wl3, const float* __restrict__ Wr3,
        _Float16* __restrict__ wtl1, _Float16* __restrict__ wtr1,
        _Float16* __restrict__ wtl2, _Float16* __restrict__ wtr2,
        _Float16* __restrict__ w3t, int gEt, int gX) {
    const int b = blockIdx.x;
    if (b < gEt) {
        int e = b * 256 + threadIdx.x;
        if (e < Et) {
            int d = (e < E) ? ei[E + e] : (e - E);
            atomicAdd(&cnt[d], 1);
        }
    } else if (b < gEt + gX) {
        int i = (b - gEt) * 256 + threadIdx.x;
        if (i < (N << 6)) {
            int n = i >> 6, k = i & 63;
            xb[i] = (_Float16)(k < F ? x[n * F + k] : 0.0f);
        }
    } else {
        int i = (b - gEt - gX) * 256 + threadIdx.x;
        if (i < 32768) {
            const float* W = (i < 16384) ? Wl1 : Wr1;
            _Float16* O = (i < 16384) ? wtl1 : wtr1;
            int loc = i & 16383;
            int n = loc >> 6, k = loc & 63;
            O[loc] = (_Float16)(k < F ? W[k * 256 + n] : 0.0f);
        } else if (i < 163840) {
            int seg = i - 32768;
            const float* W = (seg < 65536) ? Wl2 : Wr2;
            _Float16* O = (seg < 65536) ? wtl2 : wtr2;
            int loc = seg & 65535;
            int n = loc >> 8, k = loc & 255;
            O[loc] = (_Float16)W[k * 256 + n];
        } else if (i < 167936) {
            int loc = i - 163840;
            int j = loc >> 8, k = loc & 255;
            float v = (j < 6) ? Wl3[k * 6 + j] : ((j < 12) ? Wr3[k * 6 + (j - 6)] : 0.0f);
            w3t[loc] = (_Float16)v;
        }
    }
}

// ---------------- MFMA fp16 GEMM pair — m97-style async-LDS, single-buffered ----------------
// (R10 version: double-buffer variant measured ~6 us SLOWER — m99/m100 pattern)

__global__ __launch_bounds__(256) void k_gemm_pair_mfma(
        const _Float16* __restrict__ A, int M, int Kp,
        const _Float16* __restrict__ Btl, const _Float16* __restrict__ Btr,
        const float* __restrict__ bl, const float* __restrict__ br,
        _Float16* __restrict__ Cl, _Float16* __restrict__ Cr) {
    __shared__ _Float16 As[128 * 32];
    __shared__ _Float16 Bs[128 * 32];
    const int wv = threadIdx.x >> 6, lane = threadIdx.x & 63;
    const int wr = wv >> 1, wc = wv & 1;
    const int l15 = lane & 15, l4 = lane >> 4;
    const int row0 = blockIdx.x * 128;
    const int mat  = blockIdx.y >> 1;
    const int col0 = (blockIdx.y & 1) * 128;
    const _Float16* Bt = mat ? Btr : Btl;
    const float* bias  = mat ? br  : bl;
    _Float16* C        = mat ? Cr  : Cl;

    const int rl = lane >> 2;
    const int kq = (lane & 3) * 8;
    const _Float16* ga0 = A + (size_t)min(row0 + wv * 32 + rl,      M - 1) * Kp + kq;
    const _Float16* ga1 = A + (size_t)min(row0 + wv * 32 + 16 + rl, M - 1) * Kp + kq;
    const _Float16* gb0 = Bt + (size_t)(col0 + wv * 32 + rl) * Kp + kq;
    const _Float16* gb1 = Bt + (size_t)(col0 + wv * 32 + 16 + rl) * Kp + kq;
    _Float16* la0 = &As[(wv * 32) * 32];
    _Float16* la1 = &As[(wv * 32 + 16) * 32];
    _Float16* lb0 = &Bs[(wv * 32) * 32];
    _Float16* lb1 = &Bs[(wv * 32 + 16) * 32];

    f32x4 acc[4][4];
    #pragma unroll
    for (int a = 0; a < 4; a++)
        #pragma unroll
        for (int b = 0; b < 4; b++)
            acc[a][b] = (f32x4){0.f, 0.f, 0.f, 0.f};

    for (int k0 = 0; k0 < Kp; k0 += 32) {
        GLD16(ga0 + k0, la0);
        GLD16(ga1 + k0, la1);
        GLD16(gb0 + k0, lb0);
        GLD16(gb1 + k0, lb1);
        __syncthreads();
        f16x8 wf[4], xf[4];
        #pragma unroll
        for (int ct = 0; ct < 4; ct++)
            wf[ct] = *(const f16x8*)&Bs[(wc * 64 + ct * 16 + l15) * 32 + l4 * 8];
        #pragma unroll
        for (int nt = 0; nt < 4; nt++)
            xf[nt] = *(const f16x8*)&As[(wr * 64 + nt * 16 + l15) * 32 + l4 * 8];
        #pragma unroll
        for (int ct = 0; ct < 4; ct++)
            #pragma unroll
            for (int nt = 0; nt < 4; nt++)
                acc[ct][nt] = __builtin_amdgcn_mfma_f32_16x16x32_f16(
                    wf[ct], xf[nt], acc[ct][nt], 0, 0, 0);
        __syncthreads();
    }

    float4 bv[4];
    #pragma unroll
    for (int ct = 0; ct < 4; ct++)
        bv[ct] = *(const float4*)&bias[col0 + wc * 64 + ct * 16 + l4 * 4];
    #pragma unroll
    for (int nt = 0; nt < 4; nt++) {
        int node = row0 + wr * 64 + nt * 16 + l15;
        if (node < M) {
            #pragma unroll
            for (int ct = 0; ct < 4; ct++) {
                h4 hv = {(_Float16)(acc[ct][nt][0] + bv[ct].x),
                         (_Float16)(acc[ct][nt][1] + bv[ct].y),
                         (_Float16)(acc[ct][nt][2] + bv[ct].z),
                         (_Float16)(acc[ct][nt][3] + bv[ct].w)};
                *(h4*)&C[(size_t)node * 256 + col0 + wc * 64 + ct * 16 + l4 * 4] = hv;
            }
        }
    }
}

// ---------------- Layer 3 transform via MFMA ----------------

__global__ __launch_bounds__(256) void k_gemm3_mfma(
        const _Float16* __restrict__ h,
        const _Float16* __restrict__ W3t,
        const float* __restrict__ bl, const float* __restrict__ br,
        _Float16* __restrict__ l3, int N) {
    const int wave = threadIdx.x >> 6, lane = threadIdx.x & 63;
    const int l15 = lane & 15, l4 = lane >> 4;
    const int row0 = blockIdx.x * 64 + wave * 16;
    if (row0 >= N) return;

    f16x8 bfr[8];
    #pragma unroll
    for (int ks = 0; ks < 8; ks++)
        bfr[ks] = *(const f16x8*)&W3t[l15 * 256 + ks * 32 + l4 * 8];

    const int arow = min(row0 + l15, N - 1);
    const size_t abase = (size_t)arow * 256;
    f32x4 acc = (f32x4){0.f, 0.f, 0.f, 0.f};
    #pragma unroll
    for (int ks = 0; ks < 8; ks++) {
        f16x8 af = *(const f16x8*)&h[abase + ks * 32 + l4 * 8];
        acc = __builtin_amdgcn_mfma_f32_16x16x32_f16(af, bfr[ks], acc, 0, 0, 0);
    }
    const float bv = (l15 < 6) ? bl[l15] : ((l15 < 12) ? br[l15 - 6] : 0.0f);
    #pragma unroll
    for (int r = 0; r < 4; r++) {
        int gr = row0 + l4 * 4 + r;
        if (gr < N && l15 < 12)
            l3[(size_t)gr * 16 + l15] = (_Float16)(acc[r] + bv);
    }
}

// ---------------- Aggregation layers 1&2 (H=4, C=64), fp16, online softmax ----------------
// R11: no serial tail. Every iteration is a full 8-edge batch with clamped indices
// (idx = min(j+e, end-1)) and -INF logit masking for the overhang. All gathers issue
// 8-deep regardless of degree -> dependent-load latency of the old serial tail is gone.
// Trade: ~27% more VALU (masked lanes), bought against ~40% stall time.

__global__ __launch_bounds__(256) void k_agg256(const _Float16* __restrict__ xl,
                                                const _Float16* __restrict__ xr,
                                                const int* __restrict__ row_ptr,
                                                const int* __restrict__ src_sorted,
                                                const float* __restrict__ att,
                                                const float* __restrict__ bias,
                                                _Float16* __restrict__ h_out, int N) {
    const int wave = threadIdx.x >> 6;
    const int lane = threadIdx.x & 63;
    const int n = __builtin_amdgcn_readfirstlane(blockIdx.x * 4 + wave);
    if (n >= N) return;
    const int ci = lane * 4;
    const h4 xr4 = *(const h4*)&xr[(size_t)n * 256 + ci];
    const float4 at4 = *(const float4*)&att[ci];
    const h2 ata = {(_Float16)(at4.x * LOG2E), (_Float16)(at4.y * LOG2E)};
    const h2 atb = {(_Float16)(at4.z * LOG2E), (_Float16)(at4.w * LOG2E)};
    float a0 = 0.f, a1 = 0.f, a2 = 0.f, a3 = 0.f;
    float m = -INFINITY, s = 0.0f;
    const int beg = row_ptr[n], end = row_ptr[n + 1];

    int j = beg;
    h4 v[8], vn[8];
    #pragma unroll
    for (int e = 0; e < 8; e++) {
        int idx = j + e;
        idx = idx < end ? idx : end - 1;
        int sv = src_sorted[idx];                     // uniform -> s_load
        v[e] = *(const h4*)&xl[(size_t)sv * 256 + ci];
    }
    while (true) {
        const int jn = j + 8;
        const bool hasN = (jn < end);
        if (hasN) {
            #pragma unroll
            for (int e = 0; e < 8; e++) {
                int idx = jn + e;
                idx = idx < end ? idx : end - 1;
                int sv = src_sorted[idx];
                vn[e] = *(const h4*)&xl[(size_t)sv * 256 + ci];
            }
        }
        float lg[8];
        #pragma unroll
        for (int e = 0; e < 8; e++) {
            h4 t = v[e] + xr4;
            h4 lk = __builtin_elementwise_max(t, t * (_Float16)NEG_SLOPE);
            h2 lo = __builtin_shufflevector(lk, lk, 0, 1);
            h2 hi = __builtin_shufflevector(lk, lk, 2, 3);
            lg[e] = __builtin_amdgcn_fdot2(lo, ata,
                        __builtin_amdgcn_fdot2(hi, atb, 0.0f, false), false);
        }
        #pragma unroll
        for (int e = 0; e < 8; e++) lg[e] = rowsum16(lg[e]);
        #pragma unroll
        for (int e = 0; e < 8; e++)
            if (j + e >= end) lg[e] = -INFINITY;      // uniform mask -> s_cselect
        float bm = fmaxf(fmaxf(fmaxf(lg[0], lg[1]), fmaxf(lg[2], lg[3])),
                         fmaxf(fmaxf(lg[4], lg[5]), fmaxf(lg[6], lg[7])));
        float nm = fmaxf(m, bm);
        float sc = __builtin_amdgcn_exp2f(m - nm);
        a0 *= sc; a1 *= sc; a2 *= sc; a3 *= sc;
        float ps = 0.f;
        #pragma unroll
        for (int e = 0; e < 8; e++) {
            float p = __builtin_amdgcn_exp2f(lg[e] - nm);
            ps += p;
            a0 = fmaf(p, (float)v[e].x, a0);
            a1 = fmaf(p, (float)v[e].y, a1);
            a2 = fmaf(p, (float)v[e].z, a2);
            a3 = fmaf(p, (float)v[e].w, a3);
        }
        s = s * sc + ps;
        m = nm;
        if (!hasN) break;
        #pragma unroll
        for (int e = 0; e < 8; e++) v[e] = vn[e];
        j = jn;
    }
    const float inv = 1.0f / s;
    const float4 bv = *(const float4*)&bias[ci];
    float o0 = a0 * inv + bv.x;
    float o1 = a1 * inv + bv.y;
    float o2 = a2 * inv + bv.z;
    float o3 = a3 * inv + bv.w;
    o0 = o0 > 0.f ? o0 : (__expf(o0) - 1.f);
    o1 = o1 > 0.f ? o1 : (__expf(o1) - 1.f);
    o2 = o2 > 0.f ? o2 : (__expf(o2) - 1.f);
    o3 = o3 > 0.f ? o3 : (__expf(o3) - 1.f);
    h4 hv = {(_Float16)o0, (_Float16)o1, (_Float16)o2, (_Float16)o3};
    *(h4*)&h_out[(size_t)n * 256 + ci] = hv;
}

// ---------------- Layer 3 aggregation (H=6, C=1, mean over heads) ----------------
// R11: one thread per node but edges processed in 8-deep clamped batches so the
// (src_sorted -> l3 row) dependent chains overlap; single 16B f16x8 row load;
// block 256. Previous version was a fully serial ~11-iteration latency chain at
// ~3 waves/CU occupancy.

__global__ __launch_bounds__(256) void k_agg3(const _Float16* __restrict__ l3,
                                              const int* __restrict__ row_ptr,
                                              const int* __restrict__ src_sorted,
                                              const float* __restrict__ att3,
                                              const float* __restrict__ bias3,
                                              float* __restrict__ out, int N) {
    int n = blockIdx.x * 256 + threadIdx.x;
    if (n >= N) return;
    const h4* pn = (const h4*)&l3[(size_t)n * 16];
    h4 q1 = pn[1], q2 = pn[2];
    float xrv[6];
    xrv[0] = (float)q1.z; xrv[1] = (float)q1.w;
    xrv[2] = (float)q2.x; xrv[3] = (float)q2.y;
    xrv[4] = (float)q2.z; xrv[5] = (float)q2.w;
    float attv[6], m[6], s[6], acc[6];
    #pragma unroll
    for (int k = 0; k < 6; k++) {
        attv[k] = att3[k] * LOG2E;
        m[k] = -INFINITY; s[k] = 0.0f; acc[k] = 0.0f;
    }
    const int beg = row_ptr[n], end = row_ptr[n + 1];
    for (int j = beg; j < end; j += 8) {
        f16x8 u[8];
        #pragma unroll
        for (int e = 0; e < 8; e++) {
            int idx = j + e;
            idx = idx < end ? idx : end - 1;
            int sv = src_sorted[idx];
            u[e] = *(const f16x8*)&l3[(size_t)sv * 16];
        }
        #pragma unroll
        for (int e = 0; e < 8; e++) {
            const bool valid = (j + e) < end;
            float xlv[6];
            #pragma unroll
            for (int k = 0; k < 6; k++) xlv[k] = (float)u[e][k];
            #pragma unroll
            for (int k = 0; k < 6; k++) {
                float tt = xlv[k] + xrv[k];
                float lr = fmaxf(tt, NEG_SLOPE * tt);
                float logit = valid ? (attv[k] * lr) : -INFINITY;
                float nm = fmaxf(m[k], logit);
                float sc = __builtin_amdgcn_exp2f(m[k] - nm);
                float p  = __builtin_amdgcn_exp2f(logit - nm);
                acc[k] = acc[k] * sc + p * xlv[k];
                s[k]   = s[k] * sc + p;
                m[k]   = nm;
            }
        }
    }
    float o = 0.0f;
    #pragma unroll
    for (int k = 0; k < 6; k++) o += acc[k] / s[k];
    out[n] = o * (1.0f / 6.0f) + bias3[0];
}

// ---------------- launch ----------------

extern "C" void kernel_launch(void* const* d_in, const int* in_sizes, int n_in,
                              void* d_out, int out_size, void* d_ws, size_t ws_size,
                              hipStream_t stream) {
    const float* x    = (const float*)d_in[0];
    const int*   ei   = (const int*)  d_in[1];
    const float* Wl1  = (const float*)d_in[2];
    const float* bl1  = (const float*)d_in[3];
    const float* Wr1  = (const float*)d_in[4];
    const float* br1  = (const float*)d_in[5];
    const float* att1 = (const float*)d_in[6];
    const float* bias1= (const float*)d_in[7];
    const float* Wl2  = (const float*)d_in[8];
    const float* bl2  = (const float*)d_in[9];
    const float* Wr2  = (const float*)d_in[10];
    const float* br2  = (const float*)d_in[11];
    const float* att2 = (const float*)d_in[12];
    const float* bias2= (const float*)d_in[13];
    const float* Wl3  = (const float*)d_in[14];
    const float* bl3  = (const float*)d_in[15];
    const float* Wr3  = (const float*)d_in[16];
    const float* br3  = (const float*)d_in[17];
    const float* att3 = (const float*)d_in[18];
    const float* bias3= (const float*)d_in[19];

    const int F  = in_sizes[2] / 256;   // 58
    const int N  = in_sizes[0] / F;     // 50000
    const int E  = in_sizes[1] / 2;     // 500000
    const int Et = E + N;

    char* ws = (char*)d_ws;
    size_t off = 0;
    auto carve = [&](size_t bytes) -> char* {
        char* p = ws + off;
        off = (off + bytes + 255) & ~(size_t)255;
        return p;
    };
    _Float16* xb   = (_Float16*)carve((size_t)N * 64 * 2);
    _Float16* xlb  = (_Float16*)carve((size_t)N * 256 * 2);
    _Float16* xrb  = (_Float16*)carve((size_t)N * 256 * 2);
    _Float16* hb   = (_Float16*)carve((size_t)N * 256 * 2);
    _Float16* wtl1 = (_Float16*)carve(256 * 64 * 2);
    _Float16* wtr1 = (_Float16*)carve(256 * 64 * 2);
    _Float16* wtl2 = (_Float16*)carve(256 * 256 * 2);
    _Float16* wtr2 = (_Float16*)carve(256 * 256 * 2);
    _Float16* w3t  = (_Float16*)carve(16 * 256 * 2);
    _Float16* l3   = (_Float16*)carve((size_t)N * 16 * 2);
    int* cnt        = (int*)carve((size_t)N * 4);
    int* row_ptr    = (int*)carve((size_t)(N + 1) * 4);
    int* cursor     = (int*)carve((size_t)N * 4);
    int* src_sorted = (int*)carve((size_t)Et * 4);
    int* bsums      = (int*)carve(1024 * 4);

    const int gN  = (N + 255) / 256;
    const int gEt = (Et + 255) / 256;
    const int gX  = ((N << 6) + 255) / 256;
    const int gW  = (N + 3) / 4;

    // --- fused prep (count + casts) after zeroing cnt ---
    hipMemsetAsync(cnt, 0, (size_t)N * 4, stream);
    k_prep<<<gEt + gX + 656, 256, 0, stream>>>(ei, E, Et, cnt, x, xb, N, F,
                                               Wl1, Wr1, Wl2, Wr2, Wl3, Wr3,
                                               wtl1, wtr1, wtl2, wtr2, w3t, gEt, gX);

    // --- CSR scan + scatter ---
    k_scan_block<<<gN, 256, 0, stream>>>(cnt, row_ptr, bsums, N);
    k_scan_bsums<<<1, 256, 0, stream>>>(bsums, gN);
    k_scan_add<<<gN, 256, 0, stream>>>(row_ptr, bsums, cursor, N, Et);
    k_scatter<<<gEt, 256, 0, stream>>>(ei, E, Et, cursor, src_sorted);

    dim3 gemm_grid((N + 127) / 128, 4);

    // --- Layer 1 ---
    k_gemm_pair_mfma<<<gemm_grid, 256, 0, stream>>>(xb, N, 64, wtl1, wtr1, bl1, br1, xlb, xrb);
    k_agg256<<<gW, 256, 0, stream>>>(xlb, xrb, row_ptr, src_sorted, att1, bias1, hb, N);

    // --- Layer 2 ---
    k_gemm_pair_mfma<<<gemm_grid, 256, 0, stream>>>(hb, N, 256, wtl2, wtr2, bl2, br2, xlb, xrb);
    k_agg256<<<gW, 256, 0, stream>>>(xlb, xrb, row_ptr, src_sorted, att2, bias2, hb, N);

    // --- Layer 3 ---
    k_gemm3_mfma<<<(N + 63) / 64, 256, 0, stream>>>(hb, w3t, bl3, br3, l3, N);
    k_agg3<<<(N + 255) / 256, 256, 0, stream>>>(l3, row_ptr, src_sorted, att3, bias3,
                                                (float*)d_out, N);
}

// Round 2
// 332.152 us; speedup vs baseline: 1.0103x; 1.0103x over previous
//
#include <hip/hip_runtime.h>
#include <math.h>

#define NEG_SLOPE 0.2f
#define LOG2E 1.4426950408889634f

typedef __attribute__((ext_vector_type(2))) _Float16 h2;
typedef __attribute__((ext_vector_type(4))) _Float16 h4;
typedef __attribute__((ext_vector_type(8))) _Float16 f16x8;
typedef __attribute__((ext_vector_type(4))) float f32x4;

typedef const __attribute__((address_space(1))) unsigned int* gu32p;
typedef __attribute__((address_space(3))) unsigned int* lu32p;

#define GLD16(g, l) __builtin_amdgcn_global_load_lds((gu32p)(g), (lu32p)(l), 16, 0, 0)

template<int CTRL>
__device__ __forceinline__ float dpp_add_f32(float x) {
    int y = __builtin_amdgcn_update_dpp(0, __float_as_int(x), CTRL, 0xF, 0xF, true);
    return x + __int_as_float(y);
}
__device__ __forceinline__ float rowsum16(float x) {
    x = dpp_add_f32<0xB1>(x);
    x = dpp_add_f32<0x4E>(x);
    x = dpp_add_f32<0x124>(x);
    x = dpp_add_f32<0x128>(x);
    return x;
}

// ---------------- CSR build ----------------

__global__ __launch_bounds__(256) void k_scan_block(const int* __restrict__ cnt,
                                                    int* __restrict__ out,
                                                    int* __restrict__ bsums, int n) {
    __shared__ int tmp[256];
    int t = threadIdx.x;
    int i = blockIdx.x * 256 + t;
    int v = (i < n) ? cnt[i] : 0;
    tmp[t] = v;
    __syncthreads();
    for (int d = 1; d < 256; d <<= 1) {
        int add = (t >= d) ? tmp[t - d] : 0;
        __syncthreads();
        tmp[t] += add;
        __syncthreads();
    }
    if (i < n) out[i] = tmp[t] - v;
    if (t == 255) bsums[blockIdx.x] = tmp[t];
}

__global__ __launch_bounds__(256) void k_scan_bsums(int* bsums, int nb) {
    __shared__ int tmp[256];
    int t = threadIdx.x;
    int v = (t < nb) ? bsums[t] : 0;
    tmp[t] = v;
    __syncthreads();
    for (int d = 1; d < 256; d <<= 1) {
        int add = (t >= d) ? tmp[t - d] : 0;
        __syncthreads();
        tmp[t] += add;
        __syncthreads();
    }
    if (t < nb) bsums[t] = tmp[t] - v;
}

__global__ __launch_bounds__(256) void k_scan_add(int* __restrict__ out,
                                                  const int* __restrict__ bsums,
                                                  int* __restrict__ cursor,
                                                  int n, int total) {
    int i = blockIdx.x * 256 + threadIdx.x;
    if (i < n) {
        int v = out[i] + bsums[blockIdx.x];
        out[i] = v;
        cursor[i] = v;
    }
    if (i == 0) out[n] = total;
}

__global__ __launch_bounds__(256) void k_scatter(const int* __restrict__ ei, int E, int Et,
                                                 int* __restrict__ cursor,
                                                 int* __restrict__ src_sorted) {
    int e = blockIdx.x * 256 + threadIdx.x;
    if (e < Et) {
        int s, d;
        if (e < E) { s = ei[e]; d = ei[E + e]; } else { s = d = e - E; }
        int pos = atomicAdd(&cursor[d], 1);
        src_sorted[pos] = s;
    }
}

// ---------------- fused prep: edge count + x cast + all weight casts ----------------

__global__ __launch_bounds__(256) void k_prep(
        const int* __restrict__ ei, int E, int Et, int* __restrict__ cnt,
        const float* __restrict__ x, _Float16* __restrict__ xb, int N, int F,
        const float* __restrict__ Wl1, const float* __restrict__ Wr1,
        const float* __restrict__ Wl2, const float* __restrict__ Wr2,
        const float* __restrict__ Wl3, const float* __restrict__ Wr3,
        _Float16* __restrict__ wtl1, _Float16* __restrict__ wtr1,
        _Float16* __restrict__ wtl2, _Float16* __restrict__ wtr2,
        _Float16* __restrict__ w3t, int gEt, int gX) {
    const int b = blockIdx.x;
    if (b < gEt) {
        int e = b * 256 + threadIdx.x;
        if (e < Et) {
            int d = (e < E) ? ei[E + e] : (e - E);
            atomicAdd(&cnt[d], 1);
        }
    } else if (b < gEt + gX) {
        int i = (b - gEt) * 256 + threadIdx.x;
        if (i < (N << 6)) {
            int n = i >> 6, k = i & 63;
            xb[i] = (_Float16)(k < F ? x[n * F + k] : 0.0f);
        }
    } else {
        int i = (b - gEt - gX) * 256 + threadIdx.x;
        if (i < 32768) {
            const float* W = (i < 16384) ? Wl1 : Wr1;
            _Float16* O = (i < 16384) ? wtl1 : wtr1;
            int loc = i & 16383;
            int n = loc >> 6, k = loc & 63;
            O[loc] = (_Float16)(k < F ? W[k * 256 + n] : 0.0f);
        } else if (i < 163840) {
            int seg = i - 32768;
            const float* W = (seg < 65536) ? Wl2 : Wr2;
            _Float16* O = (seg < 65536) ? wtl2 : wtr2;
            int loc = seg & 65535;
            int n = loc >> 8, k = loc & 255;
            O[loc] = (_Float16)W[k * 256 + n];
        } else if (i < 167936) {
            int loc = i - 163840;
            int j = loc >> 8, k = loc & 255;
            float v = (j < 6) ? Wl3[k * 6 + j] : ((j < 12) ? Wr3[k * 6 + (j - 6)] : 0.0f);
            w3t[loc] = (_Float16)v;
        }
    }
}

// ---------------- MFMA fp16 GEMM pair — m97-style async-LDS, single-buffered ----------------
// (R10 version: double-buffer variant measured ~6 us SLOWER — m99/m100 pattern)

__global__ __launch_bounds__(256) void k_gemm_pair_mfma(
        const _Float16* __restrict__ A, int M, int Kp,
        const _Float16* __restrict__ Btl, const _Float16* __restrict__ Btr,
        const float* __restrict__ bl, const float* __restrict__ br,
        _Float16* __restrict__ Cl, _Float16* __restrict__ Cr) {
    __shared__ _Float16 As[128 * 32];
    __shared__ _Float16 Bs[128 * 32];
    const int wv = threadIdx.x >> 6, lane = threadIdx.x & 63;
    const int wr = wv >> 1, wc = wv & 1;
    const int l15 = lane & 15, l4 = lane >> 4;
    const int row0 = blockIdx.x * 128;
    const int mat  = blockIdx.y >> 1;
    const int col0 = (blockIdx.y & 1) * 128;
    const _Float16* Bt = mat ? Btr : Btl;
    const float* bias  = mat ? br  : bl;
    _Float16* C        = mat ? Cr  : Cl;

    const int rl = lane >> 2;
    const int kq = (lane & 3) * 8;
    const _Float16* ga0 = A + (size_t)min(row0 + wv * 32 + rl,      M - 1) * Kp + kq;
    const _Float16* ga1 = A + (size_t)min(row0 + wv * 32 + 16 + rl, M - 1) * Kp + kq;
    const _Float16* gb0 = Bt + (size_t)(col0 + wv * 32 + rl) * Kp + kq;
    const _Float16* gb1 = Bt + (size_t)(col0 + wv * 32 + 16 + rl) * Kp + kq;
    _Float16* la0 = &As[(wv * 32) * 32];
    _Float16* la1 = &As[(wv * 32 + 16) * 32];
    _Float16* lb0 = &Bs[(wv * 32) * 32];
    _Float16* lb1 = &Bs[(wv * 32 + 16) * 32];

    f32x4 acc[4][4];
    #pragma unroll
    for (int a = 0; a < 4; a++)
        #pragma unroll
        for (int b = 0; b < 4; b++)
            acc[a][b] = (f32x4){0.f, 0.f, 0.f, 0.f};

    for (int k0 = 0; k0 < Kp; k0 += 32) {
        GLD16(ga0 + k0, la0);
        GLD16(ga1 + k0, la1);
        GLD16(gb0 + k0, lb0);
        GLD16(gb1 + k0, lb1);
        __syncthreads();
        f16x8 wf[4], xf[4];
        #pragma unroll
        for (int ct = 0; ct < 4; ct++)
            wf[ct] = *(const f16x8*)&Bs[(wc * 64 + ct * 16 + l15) * 32 + l4 * 8];
        #pragma unroll
        for (int nt = 0; nt < 4; nt++)
            xf[nt] = *(const f16x8*)&As[(wr * 64 + nt * 16 + l15) * 32 + l4 * 8];
        #pragma unroll
        for (int ct = 0; ct < 4; ct++)
            #pragma unroll
            for (int nt = 0; nt < 4; nt++)
                acc[ct][nt] = __builtin_amdgcn_mfma_f32_16x16x32_f16(
                    wf[ct], xf[nt], acc[ct][nt], 0, 0, 0);
        __syncthreads();
    }

    float4 bv[4];
    #pragma unroll
    for (int ct = 0; ct < 4; ct++)
        bv[ct] = *(const float4*)&bias[col0 + wc * 64 + ct * 16 + l4 * 4];
    #pragma unroll
    for (int nt = 0; nt < 4; nt++) {
        int node = row0 + wr * 64 + nt * 16 + l15;
        if (node < M) {
            #pragma unroll
            for (int ct = 0; ct < 4; ct++) {
                h4 hv = {(_Float16)(acc[ct][nt][0] + bv[ct].x),
                         (_Float16)(acc[ct][nt][1] + bv[ct].y),
                         (_Float16)(acc[ct][nt][2] + bv[ct].z),
                         (_Float16)(acc[ct][nt][3] + bv[ct].w)};
                *(h4*)&C[(size_t)node * 256 + col0 + wc * 64 + ct * 16 + l4 * 4] = hv;
            }
        }
    }
}

// ---------------- Layer 3 transform via MFMA ----------------

__global__ __launch_bounds__(256) void k_gemm3_mfma(
        const _Float16* __restrict__ h,
        const _Float16* __restrict__ W3t,
        const float* __restrict__ bl, const float* __restrict__ br,
        _Float16* __restrict__ l3, int N) {
    const int wave = threadIdx.x >> 6, lane = threadIdx.x & 63;
    const int l15 = lane & 15, l4 = lane >> 4;
    const int row0 = blockIdx.x * 64 + wave * 16;
    if (row0 >= N) return;

    f16x8 bfr[8];
    #pragma unroll
    for (int ks = 0; ks < 8; ks++)
        bfr[ks] = *(const f16x8*)&W3t[l15 * 256 + ks * 32 + l4 * 8];

    const int arow = min(row0 + l15, N - 1);
    const size_t abase = (size_t)arow * 256;
    f32x4 acc = (f32x4){0.f, 0.f, 0.f, 0.f};
    #pragma unroll
    for (int ks = 0; ks < 8; ks++) {
        f16x8 af = *(const f16x8*)&h[abase + ks * 32 + l4 * 8];
        acc = __builtin_amdgcn_mfma_f32_16x16x32_f16(af, bfr[ks], acc, 0, 0, 0);
    }
    const float bv = (l15 < 6) ? bl[l15] : ((l15 < 12) ? br[l15 - 6] : 0.0f);
    #pragma unroll
    for (int r = 0; r < 4; r++) {
        int gr = row0 + l4 * 4 + r;
        if (gr < N && l15 < 12)
            l3[(size_t)gr * 16 + l15] = (_Float16)(acc[r] + bv);
    }
}

// ---------------- Aggregation layers 1&2 (H=4, C=64), fp16, online softmax ----------------
// R12: unmasked full batches (R10 structure — no rounded-up VALU work), plus:
//  (a) tail preload: the rem = deg&7 tail gathers are issued FIRST (uniform-guarded,
//      no wasted rows), so they are in flight for the wave's entire lifetime;
//  (b) batched tail compute: rem independent logits + ONE rescale pass, replacing
//      rem sequential online-softmax chains.
// R11 lesson: masked batches cost +45% edge-VALU (edge-VALU ~16us of 50us) — never
// round work up; buy latency with loads in flight, not lanes.

__global__ __launch_bounds__(256) void k_agg256(const _Float16* __restrict__ xl,
                                                const _Float16* __restrict__ xr,
                                                const int* __restrict__ row_ptr,
                                                const int* __restrict__ src_sorted,
                                                const float* __restrict__ att,
                                                const float* __restrict__ bias,
                                                _Float16* __restrict__ h_out, int N) {
    const int wave = threadIdx.x >> 6;
    const int lane = threadIdx.x & 63;
    const int n = __builtin_amdgcn_readfirstlane(blockIdx.x * 4 + wave);
    if (n >= N) return;
    const int ci = lane * 4;
    const h4 xr4 = *(const h4*)&xr[(size_t)n * 256 + ci];
    const float4 at4 = *(const float4*)&att[ci];
    const h2 ata = {(_Float16)(at4.x * LOG2E), (_Float16)(at4.y * LOG2E)};
    const h2 atb = {(_Float16)(at4.z * LOG2E), (_Float16)(at4.w * LOG2E)};
    float a0 = 0.f, a1 = 0.f, a2 = 0.f, a3 = 0.f;
    float m = -INFINITY, s = 0.0f;
    const int beg = row_ptr[n], end = row_ptr[n + 1];
    const int rem = (end - beg) & 7;
    const int tb  = end - rem;

    // (a) tail preload — issued before everything else, guarded so no extra traffic
    h4 vt[7];
    #pragma unroll
    for (int e = 0; e < 7; e++) {
        if (e < rem) {
            int sv = src_sorted[tb + e];              // uniform -> s_load
            vt[e] = *(const h4*)&xl[(size_t)sv * 256 + ci];
        }
    }

    int j = beg;
    h4 v[8], vn[8];
    bool has = (j + 8 <= tb);
    if (has) {
        #pragma unroll
        for (int e = 0; e < 8; e++) {
            int sv = src_sorted[j + e];
            v[e] = *(const h4*)&xl[(size_t)sv * 256 + ci];
        }
    }
    while (has) {
        const int jn = j + 8;
        const bool hasN = (jn + 8 <= tb);
        if (hasN) {
            #pragma unroll
            for (int e = 0; e < 8; e++) {
                int sv = src_sorted[jn + e];
                vn[e] = *(const h4*)&xl[(size_t)sv * 256 + ci];
            }
        }
        float lg[8];
        #pragma unroll
        for (int e = 0; e < 8; e++) {
            h4 t = v[e] + xr4;
            h4 lk = __builtin_elementwise_max(t, t * (_Float16)NEG_SLOPE);
            h2 lo = __builtin_shufflevector(lk, lk, 0, 1);
            h2 hi = __builtin_shufflevector(lk, lk, 2, 3);
            lg[e] = __builtin_amdgcn_fdot2(lo, ata,
                        __builtin_amdgcn_fdot2(hi, atb, 0.0f, false), false);
        }
        #pragma unroll
        for (int e = 0; e < 8; e++) lg[e] = rowsum16(lg[e]);
        float bm = fmaxf(fmaxf(fmaxf(lg[0], lg[1]), fmaxf(lg[2], lg[3])),
                         fmaxf(fmaxf(lg[4], lg[5]), fmaxf(lg[6], lg[7])));
        float nm = fmaxf(m, bm);
        float sc = __builtin_amdgcn_exp2f(m - nm);
        a0 *= sc; a1 *= sc; a2 *= sc; a3 *= sc;
        float ps = 0.f;
        #pragma unroll
        for (int e = 0; e < 8; e++) {
            float p = __builtin_amdgcn_exp2f(lg[e] - nm);
            ps += p;
            a0 = fmaf(p, (float)v[e].x, a0);
            a1 = fmaf(p, (float)v[e].y, a1);
            a2 = fmaf(p, (float)v[e].z, a2);
            a3 = fmaf(p, (float)v[e].w, a3);
        }
        s = s * sc + ps;
        m = nm;
        if (hasN) {
            #pragma unroll
            for (int e = 0; e < 8; e++) v[e] = vn[e];
        }
        j = jn;
        has = hasN;
    }

    // (b) batched tail: rem independent logits, ONE rescale+accumulate pass
    if (rem) {
        float lg[7];
        #pragma unroll
        for (int e = 0; e < 7; e++) {
            if (e < rem) {
                h4 t = vt[e] + xr4;
                h4 lk = __builtin_elementwise_max(t, t * (_Float16)NEG_SLOPE);
                h2 lo = __builtin_shufflevector(lk, lk, 0, 1);
                h2 hi = __builtin_shufflevector(lk, lk, 2, 3);
                float d = __builtin_amdgcn_fdot2(lo, ata,
                              __builtin_amdgcn_fdot2(hi, atb, 0.0f, false), false);
                lg[e] = rowsum16(d);
            }
        }
        float bm = -INFINITY;
        #pragma unroll
        for (int e = 0; e < 7; e++)
            if (e < rem) bm = fmaxf(bm, lg[e]);
        float nm = fmaxf(m, bm);
        float sc = __builtin_amdgcn_exp2f(m - nm);
        a0 *= sc; a1 *= sc; a2 *= sc; a3 *= sc;
        float ps = 0.f;
        #pragma unroll
        for (int e = 0; e < 7; e++) {
            if (e < rem) {
                float p = __builtin_amdgcn_exp2f(lg[e] - nm);
                ps += p;
                a0 = fmaf(p, (float)vt[e].x, a0);
                a1 = fmaf(p, (float)vt[e].y, a1);
                a2 = fmaf(p, (float)vt[e].z, a2);
                a3 = fmaf(p, (float)vt[e].w, a3);
            }
        }
        s = s * sc + ps;
        m = nm;
    }

    const float inv = 1.0f / s;
    const float4 bv = *(const float4*)&bias[ci];
    float o0 = a0 * inv + bv.x;
    float o1 = a1 * inv + bv.y;
    float o2 = a2 * inv + bv.z;
    float o3 = a3 * inv + bv.w;
    o0 = o0 > 0.f ? o0 : (__expf(o0) - 1.f);
    o1 = o1 > 0.f ? o1 : (__expf(o1) - 1.f);
    o2 = o2 > 0.f ? o2 : (__expf(o2) - 1.f);
    o3 = o3 > 0.f ? o3 : (__expf(o3) - 1.f);
    h4 hv = {(_Float16)o0, (_Float16)o1, (_Float16)o2, (_Float16)o3};
    *(h4*)&h_out[(size_t)n * 256 + ci] = hv;
}

// ---------------- Layer 3 aggregation (H=6, C=1, mean over heads) ----------------
// R11 version kept (measured ~10us net win vs R10): 8-deep clamped batches, block 256.

__global__ __launch_bounds__(256) void k_agg3(const _Float16* __restrict__ l3,
                                              const int* __restrict__ row_ptr,
                                              const int* __restrict__ src_sorted,
                                              const float* __restrict__ att3,
                                              const float* __restrict__ bias3,
                                              float* __restrict__ out, int N) {
    int n = blockIdx.x * 256 + threadIdx.x;
    if (n >= N) return;
    const h4* pn = (const h4*)&l3[(size_t)n * 16];
    h4 q1 = pn[1], q2 = pn[2];
    float xrv[6];
    xrv[0] = (float)q1.z; xrv[1] = (float)q1.w;
    xrv[2] = (float)q2.x; xrv[3] = (float)q2.y;
    xrv[4] = (float)q2.z; xrv[5] = (float)q2.w;
    float attv[6], m[6], s[6], acc[6];
    #pragma unroll
    for (int k = 0; k < 6; k++) {
        attv[k] = att3[k] * LOG2E;
        m[k] = -INFINITY; s[k] = 0.0f; acc[k] = 0.0f;
    }
    const int beg = row_ptr[n], end = row_ptr[n + 1];
    for (int j = beg; j < end; j += 8) {
        f16x8 u[8];
        #pragma unroll
        for (int e = 0; e < 8; e++) {
            int idx = j + e;
            idx = idx < end ? idx : end - 1;
            int sv = src_sorted[idx];
            u[e] = *(const f16x8*)&l3[(size_t)sv * 16];
        }
        #pragma unroll
        for (int e = 0; e < 8; e++) {
            const bool valid = (j + e) < end;
            float xlv[6];
            #pragma unroll
            for (int k = 0; k < 6; k++) xlv[k] = (float)u[e][k];
            #pragma unroll
            for (int k = 0; k < 6; k++) {
                float tt = xlv[k] + xrv[k];
                float lr = fmaxf(tt, NEG_SLOPE * tt);
                float logit = valid ? (attv[k] * lr) : -INFINITY;
                float nm = fmaxf(m[k], logit);
                float sc = __builtin_amdgcn_exp2f(m[k] - nm);
                float p  = __builtin_amdgcn_exp2f(logit - nm);
                acc[k] = acc[k] * sc + p * xlv[k];
                s[k]   = s[k] * sc + p;
                m[k]   = nm;
            }
        }
    }
    float o = 0.0f;
    #pragma unroll
    for (int k = 0; k < 6; k++) o += acc[k] / s[k];
    out[n] = o * (1.0f / 6.0f) + bias3[0];
}

// ---------------- launch ----------------

extern "C" void kernel_launch(void* const* d_in, const int* in_sizes, int n_in,
                              void* d_out, int out_size, void* d_ws, size_t ws_size,
                              hipStream_t stream) {
    const float* x    = (const float*)d_in[0];
    const int*   ei   = (const int*)  d_in[1];
    const float* Wl1  = (const float*)d_in[2];
    const float* bl1  = (const float*)d_in[3];
    const float* Wr1  = (const float*)d_in[4];
    const float* br1  = (const float*)d_in[5];
    const float* att1 = (const float*)d_in[6];
    const float* bias1= (const float*)d_in[7];
    const float* Wl2  = (const float*)d_in[8];
    const float* bl2  = (const float*)d_in[9];
    const float* Wr2  = (const float*)d_in[10];
    const float* br2  = (const float*)d_in[11];
    const float* att2 = (const float*)d_in[12];
    const float* bias2= (const float*)d_in[13];
    const float* Wl3  = (const float*)d_in[14];
    const float* bl3  = (const float*)d_in[15];
    const float* Wr3  = (const float*)d_in[16];
    const float* br3  = (const float*)d_in[17];
    const float* att3 = (const float*)d_in[18];
    const float* bias3= (const float*)d_in[19];

    const int F  = in_sizes[2] / 256;   // 58
    const int N  = in_sizes[0] / F;     // 50000
    const int E  = in_sizes[1] / 2;     // 500000
    const int Et = E + N;

    char* ws = (char*)d_ws;
    size_t off = 0;
    auto carve = [&](size_t bytes) -> char* {
        char* p = ws + off;
        off = (off + bytes + 255) & ~(size_t)255;
        return p;
    };
    _Float16* xb   = (_Float16*)carve((size_t)N * 64 * 2);
    _Float16* xlb  = (_Float16*)carve((size_t)N * 256 * 2);
    _Float16* xrb  = (_Float16*)carve((size_t)N * 256 * 2);
    _Float16* hb   = (_Float16*)carve((size_t)N * 256 * 2);
    _Float16* wtl1 = (_Float16*)carve(256 * 64 * 2);
    _Float16* wtr1 = (_Float16*)carve(256 * 64 * 2);
    _Float16* wtl2 = (_Float16*)carve(256 * 256 * 2);
    _Float16* wtr2 = (_Float16*)carve(256 * 256 * 2);
    _Float16* w3t  = (_Float16*)carve(16 * 256 * 2);
    _Float16* l3   = (_Float16*)carve((size_t)N * 16 * 2);
    int* cnt        = (int*)carve((size_t)N * 4);
    int* row_ptr    = (int*)carve((size_t)(N + 1) * 4);
    int* cursor     = (int*)carve((size_t)N * 4);
    int* src_sorted = (int*)carve((size_t)Et * 4);
    int* bsums      = (int*)carve(1024 * 4);

    const int gN  = (N + 255) / 256;
    const int gEt = (Et + 255) / 256;
    const int gX  = ((N << 6) + 255) / 256;
    const int gW  = (N + 3) / 4;

    // --- fused prep (count + casts) after zeroing cnt ---
    hipMemsetAsync(cnt, 0, (size_t)N * 4, stream);
    k_prep<<<gEt + gX + 656, 256, 0, stream>>>(ei, E, Et, cnt, x, xb, N, F,
                                               Wl1, Wr1, Wl2, Wr2, Wl3, Wr3,
                                               wtl1, wtr1, wtl2, wtr2, w3t, gEt, gX);

    // --- CSR scan + scatter ---
    k_scan_block<<<gN, 256, 0, stream>>>(cnt, row_ptr, bsums, N);
    k_scan_bsums<<<1, 256, 0, stream>>>(bsums, gN);
    k_scan_add<<<gN, 256, 0, stream>>>(row_ptr, bsums, cursor, N, Et);
    k_scatter<<<gEt, 256, 0, stream>>>(ei, E, Et, cursor, src_sorted);

    dim3 gemm_grid((N + 127) / 128, 4);

    // --- Layer 1 ---
    k_gemm_pair_mfma<<<gemm_grid, 256, 0, stream>>>(xb, N, 64, wtl1, wtr1, bl1, br1, xlb, xrb);
    k_agg256<<<gW, 256, 0, stream>>>(xlb, xrb, row_ptr, src_sorted, att1, bias1, hb, N);

    // --- Layer 2 ---
    k_gemm_pair_mfma<<<gemm_grid, 256, 0, stream>>>(hb, N, 256, wtl2, wtr2, bl2, br2, xlb, xrb);
    k_agg256<<<gW, 256, 0, stream>>>(xlb, xrb, row_ptr, src_sorted, att2, bias2, hb, N);

    // --- Layer 3 ---
    k_gemm3_mfma<<<(N + 63) / 64, 256, 0, stream>>>(hb, w3t, bl3, br3, l3, N);
    k_agg3<<<(N + 255) / 256, 256, 0, stream>>>(l3, row_ptr, src_sorted, att3, bias3,
                                                (float*)d_out, N);
}

// Round 4
// 327.705 us; speedup vs baseline: 1.0240x; 1.0136x over previous
//
#include <hip/hip_runtime.h>
#include <math.h>

#define NEG_SLOPE 0.2f
#define LOG2E 1.4426950408889634f
#define MNEG 1.0e30f

typedef __attribute__((ext_vector_type(2))) _Float16 h2;
typedef __attribute__((ext_vector_type(4))) _Float16 h4;
typedef __attribute__((ext_vector_type(8))) _Float16 f16x8;
typedef __attribute__((ext_vector_type(4))) float f32x4;

typedef const __attribute__((address_space(1))) unsigned int* gu32p;
typedef __attribute__((address_space(3))) unsigned int* lu32p;

#define GLD16(g, l) __builtin_amdgcn_global_load_lds((gu32p)(g), (lu32p)(l), 16, 0, 0)

template<int CTRL>
__device__ __forceinline__ float dpp_add_f32(float x) {
    int y = __builtin_amdgcn_update_dpp(0, __float_as_int(x), CTRL, 0xF, 0xF, true);
    return x + __int_as_float(y);
}
// Sum over each aligned 8-lane group, broadcast to all 8 lanes.
// xor1 (quad_perm [1,0,3,2]) + xor2 (quad_perm [2,3,0,1]) make each quad uniform;
// row_half_mirror (0x141) then delivers the OTHER quad's value to every lane of
// the 8-group. All three are symmetric permutations — no rotation-direction
// ambiguity (R13's row_ror/row_shl broadcast was direction-sensitive and wrong).
__device__ __forceinline__ float rowsum8_bcast(float x) {
    x = dpp_add_f32<0xB1>(x);
    x = dpp_add_f32<0x4E>(x);
    x = dpp_add_f32<0x141>(x);
    return x;
}

// ---------------- CSR build ----------------

__global__ __launch_bounds__(256) void k_scan_block(const int* __restrict__ cnt,
                                                    int* __restrict__ out,
                                                    int* __restrict__ bsums, int n) {
    __shared__ int tmp[256];
    int t = threadIdx.x;
    int i = blockIdx.x * 256 + t;
    int v = (i < n) ? cnt[i] : 0;
    tmp[t] = v;
    __syncthreads();
    for (int d = 1; d < 256; d <<= 1) {
        int add = (t >= d) ? tmp[t - d] : 0;
        __syncthreads();
        tmp[t] += add;
        __syncthreads();
    }
    if (i < n) out[i] = tmp[t] - v;
    if (t == 255) bsums[blockIdx.x] = tmp[t];
}

// absorbs the bsums scan (nb <= 256) — one fewer launch.
__global__ __launch_bounds__(256) void k_scan_add(int* __restrict__ out,
                                                  const int* __restrict__ bsums,
                                                  int* __restrict__ cursor,
                                                  int n, int total, int nb) {
    __shared__ int tmp[256];
    int t = threadIdx.x;
    int v = (t < nb) ? bsums[t] : 0;
    tmp[t] = v;
    __syncthreads();
    for (int d = 1; d < 256; d <<= 1) {
        int add = (t >= d) ? tmp[t - d] : 0;
        __syncthreads();
        tmp[t] += add;
        __syncthreads();
    }
    int boff = tmp[blockIdx.x] - bsums[blockIdx.x];   // exclusive prefix of block sums
    int i = blockIdx.x * 256 + t;
    if (i < n) {
        int vv = out[i] + boff;
        out[i] = vv;
        cursor[i] = vv;
    }
    if (i == 0) out[n] = total;
}

__global__ __launch_bounds__(256) void k_scatter(const int* __restrict__ ei, int E, int Et,
                                                 int* __restrict__ cursor,
                                                 int* __restrict__ src_sorted) {
    int e = blockIdx.x * 256 + threadIdx.x;
    if (e < Et) {
        int s, d;
        if (e < E) { s = ei[e]; d = ei[E + e]; } else { s = d = e - E; }
        int pos = atomicAdd(&cursor[d], 1);
        src_sorted[pos] = s;
    }
}

// ---------------- fused prep: edge count + x cast + all weight casts ----------------

__global__ __launch_bounds__(256) void k_prep(
        const int* __restrict__ ei, int E, int Et, int* __restrict__ cnt,
        const float* __restrict__ x, _Float16* __restrict__ xb, int N, int F,
        const float* __restrict__ Wl1, const float* __restrict__ Wr1,
        const float* __restrict__ Wl2, const float* __restrict__ Wr2,
        const float* __restrict__ Wl3, const float* __restrict__ Wr3,
        _Float16* __restrict__ wtl1, _Float16* __restrict__ wtr1,
        _Float16* __restrict__ wtl2, _Float16* __restrict__ wtr2,
        _Float16* __restrict__ w3t, int gEt, int gX) {
    const int b = blockIdx.x;
    if (b < gEt) {
        int e = b * 256 + threadIdx.x;
        if (e < Et) {
            int d = (e < E) ? ei[E + e] : (e - E);
            atomicAdd(&cnt[d], 1);
        }
    } else if (b < gEt + gX) {
        int i = (b - gEt) * 256 + threadIdx.x;
        if (i < (N << 6)) {
            int n = i >> 6, k = i & 63;
            xb[i] = (_Float16)(k < F ? x[n * F + k] : 0.0f);
        }
    } else {
        int i = (b - gEt - gX) * 256 + threadIdx.x;
        if (i < 32768) {
            const float* W = (i < 16384) ? Wl1 : Wr1;
            _Float16* O = (i < 16384) ? wtl1 : wtr1;
            int loc = i & 16383;
            int n = loc >> 6, k = loc & 63;
            O[loc] = (_Float16)(k < F ? W[k * 256 + n] : 0.0f);
        } else if (i < 163840) {
            int seg = i - 32768;
            const float* W = (seg < 65536) ? Wl2 : Wr2;
            _Float16* O = (seg < 65536) ? wtl2 : wtr2;
            int loc = seg & 65535;
            int n = loc >> 8, k = loc & 255;
            O[loc] = (_Float16)W[k * 256 + n];
        } else if (i < 167936) {
            int loc = i - 163840;
            int j = loc >> 8, k = loc & 255;
            float v = (j < 6) ? Wl3[k * 6 + j] : ((j < 12) ? Wr3[k * 6 + (j - 6)] : 0.0f);
            w3t[loc] = (_Float16)v;
        }
    }
}

// ---------------- MFMA fp16 GEMM pair ----------------
// 512-thread blocks, 128 rows x 256 cols (full mat) per block, blockIdx.y = mat.
// A-tile read 2x total instead of 4x; 3 global_load_lds per K-step.
// LDS destinations are wave-uniform bases (GLD16 contract: base + lane*16B);
// the per-lane global addresses produce exactly that linear order.

__global__ __launch_bounds__(512) void k_gemm_pair_mfma(
        const _Float16* __restrict__ A, int M, int Kp,
        const _Float16* __restrict__ Btl, const _Float16* __restrict__ Btr,
        const float* __restrict__ bl, const float* __restrict__ br,
        _Float16* __restrict__ Cl, _Float16* __restrict__ Cr) {
    __shared__ _Float16 As[128 * 32];
    __shared__ _Float16 Bs[256 * 32];
    const int tid = threadIdx.x;
    const int wv = tid >> 6, lane = tid & 63;
    const int wr = wv >> 2, wc = wv & 3;
    const int l15 = lane & 15, l4 = lane >> 4;
    const int row0 = blockIdx.x * 128;
    const int mat  = blockIdx.y;
    const _Float16* Bt = mat ? Btr : Btl;
    const float* bias  = mat ? br  : bl;
    _Float16* C        = mat ? Cr  : Cl;

    const int sr = tid >> 2;            // 0..127
    const int sk = (tid & 3) * 8;       // k offset (halves)
    const _Float16* gA  = A  + (size_t)min(row0 + sr, M - 1) * Kp + sk;
    const _Float16* gB0 = Bt + (size_t)sr * Kp + sk;
    const _Float16* gB1 = Bt + (size_t)(sr + 128) * Kp + sk;
    _Float16* lA  = &As[(wv * 16) * 32];            // wave-uniform
    _Float16* lB0 = &Bs[(wv * 16) * 32];
    _Float16* lB1 = &Bs[(wv * 16 + 128) * 32];

    f32x4 acc[4][4];
    #pragma unroll
    for (int a = 0; a < 4; a++)
        #pragma unroll
        for (int b = 0; b < 4; b++)
            acc[a][b] = (f32x4){0.f, 0.f, 0.f, 0.f};

    for (int k0 = 0; k0 < Kp; k0 += 32) {
        GLD16(gA + k0, lA);
        GLD16(gB0 + k0, lB0);
        GLD16(gB1 + k0, lB1);
        __syncthreads();
        f16x8 wf[4], xf[4];
        #pragma unroll
        for (int ct = 0; ct < 4; ct++)
            wf[ct] = *(const f16x8*)&Bs[(wc * 64 + ct * 16 + l15) * 32 + l4 * 8];
        #pragma unroll
        for (int nt = 0; nt < 4; nt++)
            xf[nt] = *(const f16x8*)&As[(wr * 64 + nt * 16 + l15) * 32 + l4 * 8];
        #pragma unroll
        for (int ct = 0; ct < 4; ct++)
            #pragma unroll
            for (int nt = 0; nt < 4; nt++)
                acc[ct][nt] = __builtin_amdgcn_mfma_f32_16x16x32_f16(
                    wf[ct], xf[nt], acc[ct][nt], 0, 0, 0);
        __syncthreads();
    }

    float4 bv[4];
    #pragma unroll
    for (int ct = 0; ct < 4; ct++)
        bv[ct] = *(const float4*)&bias[wc * 64 + ct * 16 + l4 * 4];
    #pragma unroll
    for (int nt = 0; nt < 4; nt++) {
        int node = row0 + wr * 64 + nt * 16 + l15;
        if (node < M) {
            #pragma unroll
            for (int ct = 0; ct < 4; ct++) {
                h4 hv = {(_Float16)(acc[ct][nt][0] + bv[ct].x),
                         (_Float16)(acc[ct][nt][1] + bv[ct].y),
                         (_Float16)(acc[ct][nt][2] + bv[ct].z),
                         (_Float16)(acc[ct][nt][3] + bv[ct].w)};
                *(h4*)&C[(size_t)node * 256 + wc * 64 + ct * 16 + l4 * 4] = hv;
            }
        }
    }
}

// ---------------- Layer 3 transform via MFMA ----------------

__global__ __launch_bounds__(256) void k_gemm3_mfma(
        const _Float16* __restrict__ h,
        const _Float16* __restrict__ W3t,
        const float* __restrict__ bl, const float* __restrict__ br,
        _Float16* __restrict__ l3, int N) {
    const int wave = threadIdx.x >> 6, lane = threadIdx.x & 63;
    const int l15 = lane & 15, l4 = lane >> 4;
    const int row0 = blockIdx.x * 64 + wave * 16;
    if (row0 >= N) return;

    f16x8 bfr[8];
    #pragma unroll
    for (int ks = 0; ks < 8; ks++)
        bfr[ks] = *(const f16x8*)&W3t[l15 * 256 + ks * 32 + l4 * 8];

    const int arow = min(row0 + l15, N - 1);
    const size_t abase = (size_t)arow * 256;
    f32x4 acc = (f32x4){0.f, 0.f, 0.f, 0.f};
    #pragma unroll
    for (int ks = 0; ks < 8; ks++) {
        f16x8 af = *(const f16x8*)&h[abase + ks * 32 + l4 * 8];
        acc = __builtin_amdgcn_mfma_f32_16x16x32_f16(af, bfr[ks], acc, 0, 0, 0);
    }
    const float bv = (l15 < 6) ? bl[l15] : ((l15 < 12) ? br[l15 - 6] : 0.0f);
    #pragma unroll
    for (int r = 0; r < 4; r++) {
        int gr = row0 + l4 * 4 + r;
        if (gr < N && l15 < 12)
            l3[(size_t)gr * 16 + l15] = (_Float16)(acc[r] + bv);
    }
}

// ---------------- Aggregation layers 1&2 (H=4, C=64), fp16, online softmax ----------------
// Lane holds 8 channels (16B loads); lanes 0-31 = even edges, 32-63 = odd edges.
// ci = (l&7)*8 + ((l>>3)&3)*64 -> head = 8 contiguous lanes; rowsum8 (3 symmetric
// DPP stages). Each half runs an independent online softmax (m init -1e30);
// cross-half merge via __shfl_xor(…, 32) — guaranteed full-wave semantics.

__device__ __forceinline__ float edge_logit(const f16x8 v, const f16x8 xr8,
        const h2 at0, const h2 at1, const h2 at2, const h2 at3) {
    f16x8 t = v + xr8;
    f16x8 lk = __builtin_elementwise_max(t, t * (_Float16)NEG_SLOPE);
    h2 c0 = __builtin_shufflevector(lk, lk, 0, 1);
    h2 c1 = __builtin_shufflevector(lk, lk, 2, 3);
    h2 c2 = __builtin_shufflevector(lk, lk, 4, 5);
    h2 c3 = __builtin_shufflevector(lk, lk, 6, 7);
    float d = __builtin_amdgcn_fdot2(c0, at0,
              __builtin_amdgcn_fdot2(c1, at1,
              __builtin_amdgcn_fdot2(c2, at2,
              __builtin_amdgcn_fdot2(c3, at3, 0.0f, false), false), false), false);
    return rowsum8_bcast(d);
}

__device__ __forceinline__ void batch8(const f16x8 v0, const f16x8 v1,
                                       const f16x8 v2, const f16x8 v3,
                                       int pcn, int invp, bool hi,
                                       const f16x8 xr8,
                                       const h2 at0, const h2 at1,
                                       const h2 at2, const h2 at3,
                                       float* a, float& m, float& s) {
    float lg0 = -INFINITY, lg1 = -INFINITY, lg2 = -INFINITY, lg3 = -INFINITY;
    if (pcn > 0) lg0 = edge_logit(v0, xr8, at0, at1, at2, at3);
    if (pcn > 1) lg1 = edge_logit(v1, xr8, at0, at1, at2, at3);
    if (pcn > 2) lg2 = edge_logit(v2, xr8, at0, at1, at2, at3);
    if (pcn > 3) lg3 = edge_logit(v3, xr8, at0, at1, at2, at3);
    if (invp == 0) lg0 = hi ? -INFINITY : lg0;
    if (invp == 1) lg1 = hi ? -INFINITY : lg1;
    if (invp == 2) lg2 = hi ? -INFINITY : lg2;
    if (invp == 3) lg3 = hi ? -INFINITY : lg3;
    float bm = fmaxf(fmaxf(lg0, lg1), fmaxf(lg2, lg3));
    float nm = fmaxf(m, bm);
    float sc = __builtin_amdgcn_exp2f(m - nm);
    #pragma unroll
    for (int c = 0; c < 8; c++) a[c] *= sc;
    float ps = 0.f;
    if (pcn > 0) {
        float pe = __builtin_amdgcn_exp2f(lg0 - nm); ps += pe;
        #pragma unroll
        for (int c = 0; c < 8; c++) a[c] = fmaf(pe, (float)v0[c], a[c]);
    }
    if (pcn > 1) {
        float pe = __builtin_amdgcn_exp2f(lg1 - nm); ps += pe;
        #pragma unroll
        for (int c = 0; c < 8; c++) a[c] = fmaf(pe, (float)v1[c], a[c]);
    }
    if (pcn > 2) {
        float pe = __builtin_amdgcn_exp2f(lg2 - nm); ps += pe;
        #pragma unroll
        for (int c = 0; c < 8; c++) a[c] = fmaf(pe, (float)v2[c], a[c]);
    }
    if (pcn > 3) {
        float pe = __builtin_amdgcn_exp2f(lg3 - nm); ps += pe;
        #pragma unroll
        for (int c = 0; c < 8; c++) a[c] = fmaf(pe, (float)v3[c], a[c]);
    }
    s = s * sc + ps;
    m = nm;
}

__global__ __launch_bounds__(256) void k_agg256(const _Float16* __restrict__ xl,
                                                const _Float16* __restrict__ xr,
                                                const int* __restrict__ row_ptr,
                                                const int* __restrict__ src_sorted,
                                                const float* __restrict__ att,
                                                const float* __restrict__ bias,
                                                _Float16* __restrict__ h_out, int N) {
    const int wave = threadIdx.x >> 6;
    const int lane = threadIdx.x & 63;
    const int n = __builtin_amdgcn_readfirstlane(blockIdx.x * 4 + wave);
    if (n >= N) return;
    const bool hi = lane >= 32;
    const int ci = (lane & 7) * 8 + ((lane >> 3) & 3) * 64;

    const f16x8 xr8 = *(const f16x8*)&xr[(size_t)n * 256 + ci];
    const float4 af0 = *(const float4*)&att[ci];
    const float4 af1 = *(const float4*)&att[ci + 4];
    const h2 at0 = {(_Float16)(af0.x * LOG2E), (_Float16)(af0.y * LOG2E)};
    const h2 at1 = {(_Float16)(af0.z * LOG2E), (_Float16)(af0.w * LOG2E)};
    const h2 at2 = {(_Float16)(af1.x * LOG2E), (_Float16)(af1.y * LOG2E)};
    const h2 at3 = {(_Float16)(af1.z * LOG2E), (_Float16)(af1.w * LOG2E)};

    float a[8];
    #pragma unroll
    for (int c = 0; c < 8; c++) a[c] = 0.f;
    float m = -MNEG, s = 0.0f;

    const int beg = row_ptr[n], end = row_ptr[n + 1];
    const int deg = end - beg;
    const int rem = deg & 7;
    const int tb  = end - rem;                 // main loop covers [beg, tb)
    const int pc  = (rem + 1) >> 1;            // tail pairs with >=1 valid edge
    const int invp = (rem & 1) ? (pc - 1) : -1;

    // tail preload (clamped; at most one dup row per odd-degree node)
    f16x8 vt0, vt1, vt2, vt3;
    if (pc > 0) { int ia = src_sorted[tb];
                  int ib = src_sorted[min(tb + 1, end - 1)];
                  int sv = hi ? ib : ia;
                  vt0 = *(const f16x8*)&xl[(size_t)sv * 256 + ci]; }
    if (pc > 1) { int ia = src_sorted[tb + 2];
                  int ib = src_sorted[min(tb + 3, end - 1)];
                  int sv = hi ? ib : ia;
                  vt1 = *(const f16x8*)&xl[(size_t)sv * 256 + ci]; }
    if (pc > 2) { int ia = src_sorted[tb + 4];
                  int ib = src_sorted[min(tb + 5, end - 1)];
                  int sv = hi ? ib : ia;
                  vt2 = *(const f16x8*)&xl[(size_t)sv * 256 + ci]; }
    if (pc > 3) { int ia = src_sorted[tb + 6];
                  int ib = src_sorted[min(tb + 7, end - 1)];
                  int sv = hi ? ib : ia;
                  vt3 = *(const f16x8*)&xl[(size_t)sv * 256 + ci]; }

    // main loop: full 8-edge batches, 1-batch prefetch
    int j = beg;
    f16x8 v0, v1, v2, v3, w0, w1, w2, w3;
    bool has = (j + 8 <= tb);
    if (has) {
        int i0 = src_sorted[j],     i1 = src_sorted[j + 1];
        int i2 = src_sorted[j + 2], i3 = src_sorted[j + 3];
        int i4 = src_sorted[j + 4], i5 = src_sorted[j + 5];
        int i6 = src_sorted[j + 6], i7 = src_sorted[j + 7];
        int s0 = hi ? i1 : i0, s1 = hi ? i3 : i2, s2 = hi ? i5 : i4, s3 = hi ? i7 : i6;
        v0 = *(const f16x8*)&xl[(size_t)s0 * 256 + ci];
        v1 = *(const f16x8*)&xl[(size_t)s1 * 256 + ci];
        v2 = *(const f16x8*)&xl[(size_t)s2 * 256 + ci];
        v3 = *(const f16x8*)&xl[(size_t)s3 * 256 + ci];
    }
    while (has) {
        const int jn = j + 8;
        const bool hasN = (jn + 8 <= tb);
        if (hasN) {
            int i0 = src_sorted[jn],     i1 = src_sorted[jn + 1];
            int i2 = src_sorted[jn + 2], i3 = src_sorted[jn + 3];
            int i4 = src_sorted[jn + 4], i5 = src_sorted[jn + 5];
            int i6 = src_sorted[jn + 6], i7 = src_sorted[jn + 7];
            int s0 = hi ? i1 : i0, s1 = hi ? i3 : i2, s2 = hi ? i5 : i4, s3 = hi ? i7 : i6;
            w0 = *(const f16x8*)&xl[(size_t)s0 * 256 + ci];
            w1 = *(const f16x8*)&xl[(size_t)s1 * 256 + ci];
            w2 = *(const f16x8*)&xl[(size_t)s2 * 256 + ci];
            w3 = *(const f16x8*)&xl[(size_t)s3 * 256 + ci];
        }
        batch8(v0, v1, v2, v3, 4, -1, hi, xr8, at0, at1, at2, at3, a, m, s);
        if (hasN) { v0 = w0; v1 = w1; v2 = w2; v3 = w3; }
        j = jn;
        has = hasN;
    }

    if (pc)
        batch8(vt0, vt1, vt2, vt3, pc, invp, hi, xr8, at0, at1, at2, at3, a, m, s);

    // merge the two half-softmaxes via full-wave shuffle (lane ^ 32)
    float om = __shfl_xor(m, 32);
    float os = __shfl_xor(s, 32);
    float qa[8];
    #pragma unroll
    for (int c = 0; c < 8; c++) qa[c] = __shfl_xor(a[c], 32);

    float nm = fmaxf(m, om);
    float e0 = __builtin_amdgcn_exp2f(m - nm);
    float e1 = __builtin_amdgcn_exp2f(om - nm);
    float stot = s * e0 + os * e1;
    float inv = 1.0f / stot;

    const float4 b0 = *(const float4*)&bias[ci];
    const float4 b1 = *(const float4*)&bias[ci + 4];
    float bb[8] = {b0.x, b0.y, b0.z, b0.w, b1.x, b1.y, b1.z, b1.w};

    _Float16 hv[8];
    #pragma unroll
    for (int c = 0; c < 8; c++) {
        float o = (a[c] * e0 + qa[c] * e1) * inv + bb[c];
        o = o > 0.f ? o : (__expf(o) - 1.f);
        hv[c] = (_Float16)o;
    }
    if (!hi) {
        f16x8 hv8 = {hv[0], hv[1], hv[2], hv[3], hv[4], hv[5], hv[6], hv[7]};
        *(f16x8*)&h_out[(size_t)n * 256 + ci] = hv8;
    }
}

// ---------------- Layer 3 aggregation (H=6, C=1, mean over heads) ----------------

__global__ __launch_bounds__(256) void k_agg3(const _Float16* __restrict__ l3,
                                              const int* __restrict__ row_ptr,
                                              const int* __restrict__ src_sorted,
                                              const float* __restrict__ att3,
                                              const float* __restrict__ bias3,
                                              float* __restrict__ out, int N) {
    int n = blockIdx.x * 256 + threadIdx.x;
    if (n >= N) return;
    const h4* pn = (const h4*)&l3[(size_t)n * 16];
    h4 q1 = pn[1], q2 = pn[2];
    float xrv[6];
    xrv[0] = (float)q1.z; xrv[1] = (float)q1.w;
    xrv[2] = (float)q2.x; xrv[3] = (float)q2.y;
    xrv[4] = (float)q2.z; xrv[5] = (float)q2.w;
    float attv[6], m[6], s[6], acc[6];
    #pragma unroll
    for (int k = 0; k < 6; k++) {
        attv[k] = att3[k] * LOG2E;
        m[k] = -INFINITY; s[k] = 0.0f; acc[k] = 0.0f;
    }
    const int beg = row_ptr[n], end = row_ptr[n + 1];
    for (int j = beg; j < end; j += 8) {
        f16x8 u[8];
        #pragma unroll
        for (int e = 0; e < 8; e++) {
            int idx = j + e;
            idx = idx < end ? idx : end - 1;
            int sv = src_sorted[idx];
            u[e] = *(const f16x8*)&l3[(size_t)sv * 16];
        }
        #pragma unroll
        for (int e = 0; e < 8; e++) {
            const bool valid = (j + e) < end;
            float xlv[6];
            #pragma unroll
            for (int k = 0; k < 6; k++) xlv[k] = (float)u[e][k];
            #pragma unroll
            for (int k = 0; k < 6; k++) {
                float tt = xlv[k] + xrv[k];
                float lr = fmaxf(tt, NEG_SLOPE * tt);
                float logit = valid ? (attv[k] * lr) : -INFINITY;
                float nm = fmaxf(m[k], logit);
                float sc = __builtin_amdgcn_exp2f(m[k] - nm);
                float p  = __builtin_amdgcn_exp2f(logit - nm);
                acc[k] = acc[k] * sc + p * xlv[k];
                s[k]   = s[k] * sc + p;
                m[k]   = nm;
            }
        }
    }
    float o = 0.0f;
    #pragma unroll
    for (int k = 0; k < 6; k++) o += acc[k] / s[k];
    out[n] = o * (1.0f / 6.0f) + bias3[0];
}

// ---------------- launch ----------------

extern "C" void kernel_launch(void* const* d_in, const int* in_sizes, int n_in,
                              void* d_out, int out_size, void* d_ws, size_t ws_size,
                              hipStream_t stream) {
    const float* x    = (const float*)d_in[0];
    const int*   ei   = (const int*)  d_in[1];
    const float* Wl1  = (const float*)d_in[2];
    const float* bl1  = (const float*)d_in[3];
    const float* Wr1  = (const float*)d_in[4];
    const float* br1  = (const float*)d_in[5];
    const float* att1 = (const float*)d_in[6];
    const float* bias1= (const float*)d_in[7];
    const float* Wl2  = (const float*)d_in[8];
    const float* bl2  = (const float*)d_in[9];
    const float* Wr2  = (const float*)d_in[10];
    const float* br2  = (const float*)d_in[11];
    const float* att2 = (const float*)d_in[12];
    const float* bias2= (const float*)d_in[13];
    const float* Wl3  = (const float*)d_in[14];
    const float* bl3  = (const float*)d_in[15];
    const float* Wr3  = (const float*)d_in[16];
    const float* br3  = (const float*)d_in[17];
    const float* att3 = (const float*)d_in[18];
    const float* bias3= (const float*)d_in[19];

    const int F  = in_sizes[2] / 256;   // 58
    const int N  = in_sizes[0] / F;     // 50000
    const int E  = in_sizes[1] / 2;     // 500000
    const int Et = E + N;

    char* ws = (char*)d_ws;
    size_t off = 0;
    auto carve = [&](size_t bytes) -> char* {
        char* p = ws + off;
        off = (off + bytes + 255) & ~(size_t)255;
        return p;
    };
    _Float16* xb   = (_Float16*)carve((size_t)N * 64 * 2);
    _Float16* xlb  = (_Float16*)carve((size_t)N * 256 * 2);
    _Float16* xrb  = (_Float16*)carve((size_t)N * 256 * 2);
    _Float16* hb   = (_Float16*)carve((size_t)N * 256 * 2);
    _Float16* wtl1 = (_Float16*)carve(256 * 64 * 2);
    _Float16* wtr1 = (_Float16*)carve(256 * 64 * 2);
    _Float16* wtl2 = (_Float16*)carve(256 * 256 * 2);
    _Float16* wtr2 = (_Float16*)carve(256 * 256 * 2);
    _Float16* w3t  = (_Float16*)carve(16 * 256 * 2);
    _Float16* l3   = (_Float16*)carve((size_t)N * 16 * 2);
    int* cnt        = (int*)carve((size_t)N * 4);
    int* row_ptr    = (int*)carve((size_t)(N + 1) * 4);
    int* cursor     = (int*)carve((size_t)N * 4);
    int* src_sorted = (int*)carve((size_t)Et * 4);
    int* bsums      = (int*)carve(1024 * 4);

    const int gN  = (N + 255) / 256;
    const int gEt = (Et + 255) / 256;
    const int gX  = ((N << 6) + 255) / 256;
    const int gW  = (N + 3) / 4;

    // --- fused prep (count + casts) after zeroing cnt ---
    hipMemsetAsync(cnt, 0, (size_t)N * 4, stream);
    k_prep<<<gEt + gX + 656, 256, 0, stream>>>(ei, E, Et, cnt, x, xb, N, F,
                                               Wl1, Wr1, Wl2, Wr2, Wl3, Wr3,
                                               wtl1, wtr1, wtl2, wtr2, w3t, gEt, gX);

    // --- CSR scan + scatter ---
    k_scan_block<<<gN, 256, 0, stream>>>(cnt, row_ptr, bsums, N);
    k_scan_add<<<gN, 256, 0, stream>>>(row_ptr, bsums, cursor, N, Et, gN);
    k_scatter<<<gEt, 256, 0, stream>>>(ei, E, Et, cursor, src_sorted);

    dim3 gemm_grid((N + 127) / 128, 2);

    // --- Layer 1 ---
    k_gemm_pair_mfma<<<gemm_grid, 512, 0, stream>>>(xb, N, 64, wtl1, wtr1, bl1, br1, xlb, xrb);
    k_agg256<<<gW, 256, 0, stream>>>(xlb, xrb, row_ptr, src_sorted, att1, bias1, hb, N);

    // --- Layer 2 ---
    k_gemm_pair_mfma<<<gemm_grid, 512, 0, stream>>>(hb, N, 256, wtl2, wtr2, bl2, br2, xlb, xrb);
    k_agg256<<<gW, 256, 0, stream>>>(xlb, xrb, row_ptr, src_sorted, att2, bias2, hb, N);

    // --- Layer 3 ---
    k_gemm3_mfma<<<(N + 63) / 64, 256, 0, stream>>>(hb, w3t, bl3, br3, l3, N);
    k_agg3<<<(N + 255) / 256, 256, 0, stream>>>(l3, row_ptr, src_sorted, att3, bias3,
                                                (float*)d_out, N);
}

// Round 5
// 324.207 us; speedup vs baseline: 1.0350x; 1.0108x over previous
//
#include <hip/hip_runtime.h>
#include <math.h>

#define NEG_SLOPE 0.2f
#define LOG2E 1.4426950408889634f

typedef __attribute__((ext_vector_type(2))) _Float16 h2;
typedef __attribute__((ext_vector_type(4))) _Float16 h4;
typedef __attribute__((ext_vector_type(8))) _Float16 f16x8;
typedef __attribute__((ext_vector_type(4))) float f32x4;

typedef const __attribute__((address_space(1))) unsigned int* gu32p;
typedef __attribute__((address_space(3))) unsigned int* lu32p;

#define GLD16(g, l) __builtin_amdgcn_global_load_lds((gu32p)(g), (lu32p)(l), 16, 0, 0)

template<int CTRL>
__device__ __forceinline__ float dpp_add_f32(float x) {
    int y = __builtin_amdgcn_update_dpp(0, __float_as_int(x), CTRL, 0xF, 0xF, true);
    return x + __int_as_float(y);
}
__device__ __forceinline__ float rowsum16(float x) {
    x = dpp_add_f32<0xB1>(x);
    x = dpp_add_f32<0x4E>(x);
    x = dpp_add_f32<0x124>(x);
    x = dpp_add_f32<0x128>(x);
    return x;
}

// ---------------- CSR build ----------------

__global__ __launch_bounds__(256) void k_scan_block(const int* __restrict__ cnt,
                                                    int* __restrict__ out,
                                                    int* __restrict__ bsums, int n) {
    __shared__ int tmp[256];
    int t = threadIdx.x;
    int i = blockIdx.x * 256 + t;
    int v = (i < n) ? cnt[i] : 0;
    tmp[t] = v;
    __syncthreads();
    for (int d = 1; d < 256; d <<= 1) {
        int add = (t >= d) ? tmp[t - d] : 0;
        __syncthreads();
        tmp[t] += add;
        __syncthreads();
    }
    if (i < n) out[i] = tmp[t] - v;
    if (t == 255) bsums[blockIdx.x] = tmp[t];
}

// absorbs the bsums scan (nb <= 256) — one fewer launch (R13, kept: measured win).
__global__ __launch_bounds__(256) void k_scan_add(int* __restrict__ out,
                                                  const int* __restrict__ bsums,
                                                  int* __restrict__ cursor,
                                                  int n, int total, int nb) {
    __shared__ int tmp[256];
    int t = threadIdx.x;
    int v = (t < nb) ? bsums[t] : 0;
    tmp[t] = v;
    __syncthreads();
    for (int d = 1; d < 256; d <<= 1) {
        int add = (t >= d) ? tmp[t - d] : 0;
        __syncthreads();
        tmp[t] += add;
        __syncthreads();
    }
    int boff = tmp[blockIdx.x] - bsums[blockIdx.x];   // exclusive prefix of block sums
    int i = blockIdx.x * 256 + t;
    if (i < n) {
        int vv = out[i] + boff;
        out[i] = vv;
        cursor[i] = vv;
    }
    if (i == 0) out[n] = total;
}

// ---------------- fused prep: edge count + x cast + all weight casts ----------------

__global__ __launch_bounds__(256) void k_prep(
        const int* __restrict__ ei, int E, int Et, int* __restrict__ cnt,
        const float* __restrict__ x, _Float16* __restrict__ xb, int N, int F,
        const float* __restrict__ Wl1, const float* __restrict__ Wr1,
        const float* __restrict__ Wl2, const float* __restrict__ Wr2,
        const float* __restrict__ Wl3, const float* __restrict__ Wr3,
        _Float16* __restrict__ wtl1, _Float16* __restrict__ wtr1,
        _Float16* __restrict__ wtl2, _Float16* __restrict__ wtr2,
        _Float16* __restrict__ w3t, int gEt, int gX) {
    const int b = blockIdx.x;
    if (b < gEt) {
        int e = b * 256 + threadIdx.x;
        if (e < Et) {
            int d = (e < E) ? ei[E + e] : (e - E);
            atomicAdd(&cnt[d], 1);
        }
    } else if (b < gEt + gX) {
        int i = (b - gEt) * 256 + threadIdx.x;
        if (i < (N << 6)) {
            int n = i >> 6, k = i & 63;
            xb[i] = (_Float16)(k < F ? x[n * F + k] : 0.0f);
        }
    } else {
        int i = (b - gEt - gX) * 256 + threadIdx.x;
        if (i < 32768) {
            const float* W = (i < 16384) ? Wl1 : Wr1;
            _Float16* O = (i < 16384) ? wtl1 : wtr1;
            int loc = i & 16383;
            int n = loc >> 6, k = loc & 63;
            O[loc] = (_Float16)(k < F ? W[k * 256 + n] : 0.0f);
        } else if (i < 163840) {
            int seg = i - 32768;
            const float* W = (seg < 65536) ? Wl2 : Wr2;
            _Float16* O = (seg < 65536) ? wtl2 : wtr2;
            int loc = seg & 65535;
            int n = loc >> 8, k = loc & 255;
            O[loc] = (_Float16)W[k * 256 + n];
        } else if (i < 167936) {
            int loc = i - 163840;
            int j = loc >> 8, k = loc & 255;
            float v = (j < 6) ? Wl3[k * 6 + j] : ((j < 12) ? Wr3[k * 6 + (j - 6)] : 0.0f);
            w3t[loc] = (_Float16)v;
        }
    }
}

// ---------------- MFMA fp16 GEMM pair (+ optional fused edge scatter) ----------------
// R14 structure kept (measured win): 512-thread blocks, 128 rows x 256 cols per block.
// R15: blocks [0, sB) perform the edge scatter (no dependency relation with the GEMM:
// scatter needs cursor from scan_add, GEMM needs xb/weights from prep — both ready).
// Scatter's atomics/stores hide under the GEMM's MFMA phase; one launch disappears.

__global__ __launch_bounds__(512) void k_gemm_pair_mfma(
        const _Float16* __restrict__ A, int M, int Kp,
        const _Float16* __restrict__ Btl, const _Float16* __restrict__ Btr,
        const float* __restrict__ bl, const float* __restrict__ br,
        _Float16* __restrict__ Cl, _Float16* __restrict__ Cr,
        const int* __restrict__ ei, int E, int Et,
        int* __restrict__ cursor, int* __restrict__ src_sorted,
        int sB, int gX) {
    __shared__ _Float16 As[128 * 32];
    __shared__ _Float16 Bs[256 * 32];
    if (blockIdx.x < sB) {
        int e = blockIdx.x * 512 + threadIdx.x;
        if (e < Et) {
            int s, d;
            if (e < E) { s = ei[e]; d = ei[E + e]; } else { s = d = e - E; }
            int pos = atomicAdd(&cursor[d], 1);
            src_sorted[pos] = s;
        }
        return;
    }
    const int gb = blockIdx.x - sB;
    const int mat = gb >= gX;
    const int bx  = mat ? gb - gX : gb;
    const int tid = threadIdx.x;
    const int wv = tid >> 6, lane = tid & 63;
    const int wr = wv >> 2, wc = wv & 3;
    const int l15 = lane & 15, l4 = lane >> 4;
    const int row0 = bx * 128;
    const _Float16* Bt = mat ? Btr : Btl;
    const float* bias  = mat ? br  : bl;
    _Float16* C        = mat ? Cr  : Cl;

    const int sr = tid >> 2;            // 0..127
    const int sk = (tid & 3) * 8;       // k offset (halves)
    const _Float16* gA  = A  + (size_t)min(row0 + sr, M - 1) * Kp + sk;
    const _Float16* gB0 = Bt + (size_t)sr * Kp + sk;
    const _Float16* gB1 = Bt + (size_t)(sr + 128) * Kp + sk;
    _Float16* lA  = &As[(wv * 16) * 32];            // wave-uniform base
    _Float16* lB0 = &Bs[(wv * 16) * 32];
    _Float16* lB1 = &Bs[(wv * 16 + 128) * 32];

    f32x4 acc[4][4];
    #pragma unroll
    for (int a = 0; a < 4; a++)
        #pragma unroll
        for (int b = 0; b < 4; b++)
            acc[a][b] = (f32x4){0.f, 0.f, 0.f, 0.f};

    for (int k0 = 0; k0 < Kp; k0 += 32) {
        GLD16(gA + k0, lA);
        GLD16(gB0 + k0, lB0);
        GLD16(gB1 + k0, lB1);
        __syncthreads();
        f16x8 wf[4], xf[4];
        #pragma unroll
        for (int ct = 0; ct < 4; ct++)
            wf[ct] = *(const f16x8*)&Bs[(wc * 64 + ct * 16 + l15) * 32 + l4 * 8];
        #pragma unroll
        for (int nt = 0; nt < 4; nt++)
            xf[nt] = *(const f16x8*)&As[(wr * 64 + nt * 16 + l15) * 32 + l4 * 8];
        #pragma unroll
        for (int ct = 0; ct < 4; ct++)
            #pragma unroll
            for (int nt = 0; nt < 4; nt++)
                acc[ct][nt] = __builtin_amdgcn_mfma_f32_16x16x32_f16(
                    wf[ct], xf[nt], acc[ct][nt], 0, 0, 0);
        __syncthreads();
    }

    float4 bv[4];
    #pragma unroll
    for (int ct = 0; ct < 4; ct++)
        bv[ct] = *(const float4*)&bias[wc * 64 + ct * 16 + l4 * 4];
    #pragma unroll
    for (int nt = 0; nt < 4; nt++) {
        int node = row0 + wr * 64 + nt * 16 + l15;
        if (node < M) {
            #pragma unroll
            for (int ct = 0; ct < 4; ct++) {
                h4 hv = {(_Float16)(acc[ct][nt][0] + bv[ct].x),
                         (_Float16)(acc[ct][nt][1] + bv[ct].y),
                         (_Float16)(acc[ct][nt][2] + bv[ct].z),
                         (_Float16)(acc[ct][nt][3] + bv[ct].w)};
                *(h4*)&C[(size_t)node * 256 + wc * 64 + ct * 16 + l4 * 4] = hv;
            }
        }
    }
}

// ---------------- Layer 3 transform via MFMA ----------------

__global__ __launch_bounds__(256) void k_gemm3_mfma(
        const _Float16* __restrict__ h,
        const _Float16* __restrict__ W3t,
        const float* __restrict__ bl, const float* __restrict__ br,
        _Float16* __restrict__ l3, int N) {
    const int wave = threadIdx.x >> 6, lane = threadIdx.x & 63;
    const int l15 = lane & 15, l4 = lane >> 4;
    const int row0 = blockIdx.x * 64 + wave * 16;
    if (row0 >= N) return;

    f16x8 bfr[8];
    #pragma unroll
    for (int ks = 0; ks < 8; ks++)
        bfr[ks] = *(const f16x8*)&W3t[l15 * 256 + ks * 32 + l4 * 8];

    const int arow = min(row0 + l15, N - 1);
    const size_t abase = (size_t)arow * 256;
    f32x4 acc = (f32x4){0.f, 0.f, 0.f, 0.f};
    #pragma unroll
    for (int ks = 0; ks < 8; ks++) {
        f16x8 af = *(const f16x8*)&h[abase + ks * 32 + l4 * 8];
        acc = __builtin_amdgcn_mfma_f32_16x16x32_f16(af, bfr[ks], acc, 0, 0, 0);
    }
    const float bv = (l15 < 6) ? bl[l15] : ((l15 < 12) ? br[l15 - 6] : 0.0f);
    #pragma unroll
    for (int r = 0; r < 4; r++) {
        int gr = row0 + l4 * 4 + r;
        if (gr < N && l15 < 12)
            l3[(size_t)gr * 16 + l15] = (_Float16)(acc[r] + bv);
    }
}

// ---------------- Aggregation layers 1&2 (H=4, C=64), fp16, online softmax ----------------
// R15: exact R12 version (best measured: 49.6us, VGPR 44). R14's 8ch/lane repack
// regressed to 52.9us (longer fdot2 dep chain + shuffle merge) — reverted.
// Structure: 4 ch/lane; unmasked full 8-edge batches with 1-batch prefetch;
// tail preload issued first; batched tail compute with ONE rescale pass.

__global__ __launch_bounds__(256) void k_agg256(const _Float16* __restrict__ xl,
                                                const _Float16* __restrict__ xr,
                                                const int* __restrict__ row_ptr,
                                                const int* __restrict__ src_sorted,
                                                const float* __restrict__ att,
                                                const float* __restrict__ bias,
                                                _Float16* __restrict__ h_out, int N) {
    const int wave = threadIdx.x >> 6;
    const int lane = threadIdx.x & 63;
    const int n = __builtin_amdgcn_readfirstlane(blockIdx.x * 4 + wave);
    if (n >= N) return;
    const int ci = lane * 4;
    const h4 xr4 = *(const h4*)&xr[(size_t)n * 256 + ci];
    const float4 at4 = *(const float4*)&att[ci];
    const h2 ata = {(_Float16)(at4.x * LOG2E), (_Float16)(at4.y * LOG2E)};
    const h2 atb = {(_Float16)(at4.z * LOG2E), (_Float16)(at4.w * LOG2E)};
    float a0 = 0.f, a1 = 0.f, a2 = 0.f, a3 = 0.f;
    float m = -INFINITY, s = 0.0f;
    const int beg = row_ptr[n], end = row_ptr[n + 1];
    const int rem = (end - beg) & 7;
    const int tb  = end - rem;

    // tail preload — issued before everything else, guarded so no extra traffic
    h4 vt[7];
    #pragma unroll
    for (int e = 0; e < 7; e++) {
        if (e < rem) {
            int sv = src_sorted[tb + e];              // uniform -> s_load
            vt[e] = *(const h4*)&xl[(size_t)sv * 256 + ci];
        }
    }

    int j = beg;
    h4 v[8], vn[8];
    bool has = (j + 8 <= tb);
    if (has) {
        #pragma unroll
        for (int e = 0; e < 8; e++) {
            int sv = src_sorted[j + e];
            v[e] = *(const h4*)&xl[(size_t)sv * 256 + ci];
        }
    }
    while (has) {
        const int jn = j + 8;
        const bool hasN = (jn + 8 <= tb);
        if (hasN) {
            #pragma unroll
            for (int e = 0; e < 8; e++) {
                int sv = src_sorted[jn + e];
                vn[e] = *(const h4*)&xl[(size_t)sv * 256 + ci];
            }
        }
        float lg[8];
        #pragma unroll
        for (int e = 0; e < 8; e++) {
            h4 t = v[e] + xr4;
            h4 lk = __builtin_elementwise_max(t, t * (_Float16)NEG_SLOPE);
            h2 lo = __builtin_shufflevector(lk, lk, 0, 1);
            h2 hi = __builtin_shufflevector(lk, lk, 2, 3);
            lg[e] = __builtin_amdgcn_fdot2(lo, ata,
                        __builtin_amdgcn_fdot2(hi, atb, 0.0f, false), false);
        }
        #pragma unroll
        for (int e = 0; e < 8; e++) lg[e] = rowsum16(lg[e]);
        float bm = fmaxf(fmaxf(fmaxf(lg[0], lg[1]), fmaxf(lg[2], lg[3])),
                         fmaxf(fmaxf(lg[4], lg[5]), fmaxf(lg[6], lg[7])));
        float nm = fmaxf(m, bm);
        float sc = __builtin_amdgcn_exp2f(m - nm);
        a0 *= sc; a1 *= sc; a2 *= sc; a3 *= sc;
        float ps = 0.f;
        #pragma unroll
        for (int e = 0; e < 8; e++) {
            float p = __builtin_amdgcn_exp2f(lg[e] - nm);
            ps += p;
            a0 = fmaf(p, (float)v[e].x, a0);
            a1 = fmaf(p, (float)v[e].y, a1);
            a2 = fmaf(p, (float)v[e].z, a2);
            a3 = fmaf(p, (float)v[e].w, a3);
        }
        s = s * sc + ps;
        m = nm;
        if (hasN) {
            #pragma unroll
            for (int e = 0; e < 8; e++) v[e] = vn[e];
        }
        j = jn;
        has = hasN;
    }

    // batched tail: rem independent logits, ONE rescale+accumulate pass
    if (rem) {
        float lg[7];
        #pragma unroll
        for (int e = 0; e < 7; e++) {
            if (e < rem) {
                h4 t = vt[e] + xr4;
                h4 lk = __builtin_elementwise_max(t, t * (_Float16)NEG_SLOPE);
                h2 lo = __builtin_shufflevector(lk, lk, 0, 1);
                h2 hi = __builtin_shufflevector(lk, lk, 2, 3);
                float d = __builtin_amdgcn_fdot2(lo, ata,
                              __builtin_amdgcn_fdot2(hi, atb, 0.0f, false), false);
                lg[e] = rowsum16(d);
            }
        }
        float bm = -INFINITY;
        #pragma unroll
        for (int e = 0; e < 7; e++)
            if (e < rem) bm = fmaxf(bm, lg[e]);
        float nm = fmaxf(m, bm);
        float sc = __builtin_amdgcn_exp2f(m - nm);
        a0 *= sc; a1 *= sc; a2 *= sc; a3 *= sc;
        float ps = 0.f;
        #pragma unroll
        for (int e = 0; e < 7; e++) {
            if (e < rem) {
                float p = __builtin_amdgcn_exp2f(lg[e] - nm);
                ps += p;
                a0 = fmaf(p, (float)vt[e].x, a0);
                a1 = fmaf(p, (float)vt[e].y, a1);
                a2 = fmaf(p, (float)vt[e].z, a2);
                a3 = fmaf(p, (float)vt[e].w, a3);
            }
        }
        s = s * sc + ps;
        m = nm;
    }

    const float inv = 1.0f / s;
    const float4 bv = *(const float4*)&bias[ci];
    float o0 = a0 * inv + bv.x;
    float o1 = a1 * inv + bv.y;
    float o2 = a2 * inv + bv.z;
    float o3 = a3 * inv + bv.w;
    o0 = o0 > 0.f ? o0 : (__expf(o0) - 1.f);
    o1 = o1 > 0.f ? o1 : (__expf(o1) - 1.f);
    o2 = o2 > 0.f ? o2 : (__expf(o2) - 1.f);
    o3 = o3 > 0.f ? o3 : (__expf(o3) - 1.f);
    h4 hv = {(_Float16)o0, (_Float16)o1, (_Float16)o2, (_Float16)o3};
    *(h4*)&h_out[(size_t)n * 256 + ci] = hv;
}

// ---------------- Layer 3 aggregation (H=6, C=1, mean over heads) ----------------

__global__ __launch_bounds__(256) void k_agg3(const _Float16* __restrict__ l3,
                                              const int* __restrict__ row_ptr,
                                              const int* __restrict__ src_sorted,
                                              const float* __restrict__ att3,
                                              const float* __restrict__ bias3,
                                              float* __restrict__ out, int N) {
    int n = blockIdx.x * 256 + threadIdx.x;
    if (n >= N) return;
    const h4* pn = (const h4*)&l3[(size_t)n * 16];
    h4 q1 = pn[1], q2 = pn[2];
    float xrv[6];
    xrv[0] = (float)q1.z; xrv[1] = (float)q1.w;
    xrv[2] = (float)q2.x; xrv[3] = (float)q2.y;
    xrv[4] = (float)q2.z; xrv[5] = (float)q2.w;
    float attv[6], m[6], s[6], acc[6];
    #pragma unroll
    for (int k = 0; k < 6; k++) {
        attv[k] = att3[k] * LOG2E;
        m[k] = -INFINITY; s[k] = 0.0f; acc[k] = 0.0f;
    }
    const int beg = row_ptr[n], end = row_ptr[n + 1];
    for (int j = beg; j < end; j += 8) {
        f16x8 u[8];
        #pragma unroll
        for (int e = 0; e < 8; e++) {
            int idx = j + e;
            idx = idx < end ? idx : end - 1;
            int sv = src_sorted[idx];
            u[e] = *(const f16x8*)&l3[(size_t)sv * 16];
        }
        #pragma unroll
        for (int e = 0; e < 8; e++) {
            const bool valid = (j + e) < end;
            float xlv[6];
            #pragma unroll
            for (int k = 0; k < 6; k++) xlv[k] = (float)u[e][k];
            #pragma unroll
            for (int k = 0; k < 6; k++) {
                float tt = xlv[k] + xrv[k];
                float lr = fmaxf(tt, NEG_SLOPE * tt);
                float logit = valid ? (attv[k] * lr) : -INFINITY;
                float nm = fmaxf(m[k], logit);
                float sc = __builtin_amdgcn_exp2f(m[k] - nm);
                float p  = __builtin_amdgcn_exp2f(logit - nm);
                acc[k] = acc[k] * sc + p * xlv[k];
                s[k]   = s[k] * sc + p;
                m[k]   = nm;
            }
        }
    }
    float o = 0.0f;
    #pragma unroll
    for (int k = 0; k < 6; k++) o += acc[k] / s[k];
    out[n] = o * (1.0f / 6.0f) + bias3[0];
}

// ---------------- launch ----------------

extern "C" void kernel_launch(void* const* d_in, const int* in_sizes, int n_in,
                              void* d_out, int out_size, void* d_ws, size_t ws_size,
                              hipStream_t stream) {
    const float* x    = (const float*)d_in[0];
    const int*   ei   = (const int*)  d_in[1];
    const float* Wl1  = (const float*)d_in[2];
    const float* bl1  = (const float*)d_in[3];
    const float* Wr1  = (const float*)d_in[4];
    const float* br1  = (const float*)d_in[5];
    const float* att1 = (const float*)d_in[6];
    const float* bias1= (const float*)d_in[7];
    const float* Wl2  = (const float*)d_in[8];
    const float* bl2  = (const float*)d_in[9];
    const float* Wr2  = (const float*)d_in[10];
    const float* br2  = (const float*)d_in[11];
    const float* att2 = (const float*)d_in[12];
    const float* bias2= (const float*)d_in[13];
    const float* Wl3  = (const float*)d_in[14];
    const float* bl3  = (const float*)d_in[15];
    const float* Wr3  = (const float*)d_in[16];
    const float* br3  = (const float*)d_in[17];
    const float* att3 = (const float*)d_in[18];
    const float* bias3= (const float*)d_in[19];

    const int F  = in_sizes[2] / 256;   // 58
    const int N  = in_sizes[0] / F;     // 50000
    const int E  = in_sizes[1] / 2;     // 500000
    const int Et = E + N;

    char* ws = (char*)d_ws;
    size_t off = 0;
    auto carve = [&](size_t bytes) -> char* {
        char* p = ws + off;
        off = (off + bytes + 255) & ~(size_t)255;
        return p;
    };
    _Float16* xb   = (_Float16*)carve((size_t)N * 64 * 2);
    _Float16* xlb  = (_Float16*)carve((size_t)N * 256 * 2);
    _Float16* xrb  = (_Float16*)carve((size_t)N * 256 * 2);
    _Float16* hb   = (_Float16*)carve((size_t)N * 256 * 2);
    _Float16* wtl1 = (_Float16*)carve(256 * 64 * 2);
    _Float16* wtr1 = (_Float16*)carve(256 * 64 * 2);
    _Float16* wtl2 = (_Float16*)carve(256 * 256 * 2);
    _Float16* wtr2 = (_Float16*)carve(256 * 256 * 2);
    _Float16* w3t  = (_Float16*)carve(16 * 256 * 2);
    _Float16* l3   = (_Float16*)carve((size_t)N * 16 * 2);
    int* cnt        = (int*)carve((size_t)N * 4);
    int* row_ptr    = (int*)carve((size_t)(N + 1) * 4);
    int* cursor     = (int*)carve((size_t)N * 4);
    int* src_sorted = (int*)carve((size_t)Et * 4);
    int* bsums      = (int*)carve(1024 * 4);

    const int gN  = (N + 255) / 256;
    const int gEt = (Et + 255) / 256;
    const int gX  = ((N << 6) + 255) / 256;
    const int gW  = (N + 3) / 4;
    const int gx1 = (N + 127) / 128;          // gemm row-blocks
    const int sB  = (Et + 511) / 512;         // scatter blocks (512 threads)

    // --- fused prep (count + casts) after zeroing cnt ---
    hipMemsetAsync(cnt, 0, (size_t)N * 4, stream);
    k_prep<<<gEt + gX + 656, 256, 0, stream>>>(ei, E, Et, cnt, x, xb, N, F,
                                               Wl1, Wr1, Wl2, Wr2, Wl3, Wr3,
                                               wtl1, wtr1, wtl2, wtr2, w3t, gEt, gX);

    // --- CSR scan ---
    k_scan_block<<<gN, 256, 0, stream>>>(cnt, row_ptr, bsums, N);
    k_scan_add<<<gN, 256, 0, stream>>>(row_ptr, bsums, cursor, N, Et, gN);

    // --- Layer 1 (scatter fused into the gemm1 launch: blocks [0,sB) scatter) ---
    k_gemm_pair_mfma<<<sB + 2 * gx1, 512, 0, stream>>>(
        xb, N, 64, wtl1, wtr1, bl1, br1, xlb, xrb,
        ei, E, Et, cursor, src_sorted, sB, gx1);
    k_agg256<<<gW, 256, 0, stream>>>(xlb, xrb, row_ptr, src_sorted, att1, bias1, hb, N);

    // --- Layer 2 ---
    k_gemm_pair_mfma<<<2 * gx1, 512, 0, stream>>>(
        hb, N, 256, wtl2, wtr2, bl2, br2, xlb, xrb,
        ei, E, Et, cursor, src_sorted, 0, gx1);
    k_agg256<<<gW, 256, 0, stream>>>(xlb, xrb, row_ptr, src_sorted, att2, bias2, hb, N);

    // --- Layer 3 ---
    k_gemm3_mfma<<<(N + 63) / 64, 256, 0, stream>>>(hb, w3t, bl3, br3, l3, N);
    k_agg3<<<(N + 255) / 256, 256, 0, stream>>>(l3, row_ptr, src_sorted, att3, bias3,
                                                (float*)d_out, N);
}

// Round 6
// 309.873 us; speedup vs baseline: 1.0829x; 1.0463x over previous
//
#include <hip/hip_runtime.h>
#include <math.h>

#define NEG_SLOPE 0.2f
#define LOG2E 1.4426950408889634f

typedef __attribute__((ext_vector_type(2))) _Float16 h2;
typedef __attribute__((ext_vector_type(4))) _Float16 h4;
typedef __attribute__((ext_vector_type(8))) _Float16 f16x8;
typedef __attribute__((ext_vector_type(4))) float f32x4;

typedef const __attribute__((address_space(1))) unsigned int* gu32p;
typedef __attribute__((address_space(3))) unsigned int* lu32p;

#define GLD16(g, l) __builtin_amdgcn_global_load_lds((gu32p)(g), (lu32p)(l), 16, 0, 0)

template<int CTRL>
__device__ __forceinline__ float dpp_add_f32(float x) {
    int y = __builtin_amdgcn_update_dpp(0, __float_as_int(x), CTRL, 0xF, 0xF, true);
    return x + __int_as_float(y);
}
__device__ __forceinline__ float rowsum16(float x) {
    x = dpp_add_f32<0xB1>(x);
    x = dpp_add_f32<0x4E>(x);
    x = dpp_add_f32<0x124>(x);
    x = dpp_add_f32<0x128>(x);
    return x;
}

// ---------------- CSR build ----------------

__global__ __launch_bounds__(256) void k_scan_block(const int* __restrict__ cnt,
                                                    int* __restrict__ out,
                                                    int* __restrict__ bsums, int n) {
    __shared__ int tmp[256];
    int t = threadIdx.x;
    int i = blockIdx.x * 256 + t;
    int v = (i < n) ? cnt[i] : 0;
    tmp[t] = v;
    __syncthreads();
    for (int d = 1; d < 256; d <<= 1) {
        int add = (t >= d) ? tmp[t - d] : 0;
        __syncthreads();
        tmp[t] += add;
        __syncthreads();
    }
    if (i < n) out[i] = tmp[t] - v;
    if (t == 255) bsums[blockIdx.x] = tmp[t];
}

// absorbs the bsums scan (nb <= 256) — one fewer launch (R13, kept: measured win).
__global__ __launch_bounds__(256) void k_scan_add(int* __restrict__ out,
                                                  const int* __restrict__ bsums,
                                                  int n, int total, int nb) {
    __shared__ int tmp[256];
    int t = threadIdx.x;
    int v = (t < nb) ? bsums[t] : 0;
    tmp[t] = v;
    __syncthreads();
    for (int d = 1; d < 256; d <<= 1) {
        int add = (t >= d) ? tmp[t - d] : 0;
        __syncthreads();
        tmp[t] += add;
        __syncthreads();
    }
    int boff = tmp[blockIdx.x] - bsums[blockIdx.x];   // exclusive prefix of block sums
    int i = blockIdx.x * 256 + t;
    if (i < n) out[i] += boff;
    if (i == 0) out[n] = total;
}

// ---------------- fused prep: edge count+rank + x cast + all weight casts ----------------
// R16: the counting atomicAdd's return value IS the in-bucket rank — store it.
// The scatter then needs no atomics at all (pos = row_ptr[d] + rank[e]).

__global__ __launch_bounds__(256) void k_prep(
        const int* __restrict__ ei, int E, int Et, int* __restrict__ cnt,
        int* __restrict__ rank,
        const float* __restrict__ x, _Float16* __restrict__ xb, int N, int F,
        const float* __restrict__ Wl1, const float* __restrict__ Wr1,
        const float* __restrict__ Wl2, const float* __restrict__ Wr2,
        const float* __restrict__ Wl3, const float* __restrict__ Wr3,
        _Float16* __restrict__ wtl1, _Float16* __restrict__ wtr1,
        _Float16* __restrict__ wtl2, _Float16* __restrict__ wtr2,
        _Float16* __restrict__ w3t, int gEt, int gX) {
    const int b = blockIdx.x;
    if (b < gEt) {
        int e = b * 256 + threadIdx.x;
        if (e < Et) {
            int d = (e < E) ? ei[E + e] : (e - E);
            rank[e] = atomicAdd(&cnt[d], 1);
        }
    } else if (b < gEt + gX) {
        int i = (b - gEt) * 256 + threadIdx.x;
        if (i < (N << 6)) {
            int n = i >> 6, k = i & 63;
            xb[i] = (_Float16)(k < F ? x[n * F + k] : 0.0f);
        }
    } else {
        int i = (b - gEt - gX) * 256 + threadIdx.x;
        if (i < 32768) {
            const float* W = (i < 16384) ? Wl1 : Wr1;
            _Float16* O = (i < 16384) ? wtl1 : wtr1;
            int loc = i & 16383;
            int n = loc >> 6, k = loc & 63;
            O[loc] = (_Float16)(k < F ? W[k * 256 + n] : 0.0f);
        } else if (i < 163840) {
            int seg = i - 32768;
            const float* W = (seg < 65536) ? Wl2 : Wr2;
            _Float16* O = (seg < 65536) ? wtl2 : wtr2;
            int loc = seg & 65535;
            int n = loc >> 8, k = loc & 255;
            O[loc] = (_Float16)W[k * 256 + n];
        } else if (i < 167936) {
            int loc = i - 163840;
            int j = loc >> 8, k = loc & 255;
            float v = (j < 6) ? Wl3[k * 6 + j] : ((j < 12) ? Wr3[k * 6 + (j - 6)] : 0.0f);
            w3t[loc] = (_Float16)v;
        }
    }
}

// ---------------- MFMA fp16 GEMM pair (+ fused atomic-free edge scatter) ----------------
// 512-thread blocks, 128 rows x 256 cols per block. Blocks [0,sB) do the scatter:
// pure load->store (rank precomputed in k_prep), no atomic RMW chain (R15's fused
// atomic scatter measured ~40us of near-idle time inside this dispatch).

__global__ __launch_bounds__(512) void k_gemm_pair_mfma(
        const _Float16* __restrict__ A, int M, int Kp,
        const _Float16* __restrict__ Btl, const _Float16* __restrict__ Btr,
        const float* __restrict__ bl, const float* __restrict__ br,
        _Float16* __restrict__ Cl, _Float16* __restrict__ Cr,
        const int* __restrict__ ei, int E, int Et,
        const int* __restrict__ row_ptr, const int* __restrict__ rank,
        int* __restrict__ src_sorted,
        int sB, int gX) {
    __shared__ _Float16 As[128 * 32];
    __shared__ _Float16 Bs[256 * 32];
    if (blockIdx.x < sB) {
        int e = blockIdx.x * 512 + threadIdx.x;
        if (e < Et) {
            int s, d;
            if (e < E) { s = ei[e]; d = ei[E + e]; } else { s = d = e - E; }
            src_sorted[row_ptr[d] + rank[e]] = s;
        }
        return;
    }
    const int gb = blockIdx.x - sB;
    const int mat = gb >= gX;
    const int bx  = mat ? gb - gX : gb;
    const int tid = threadIdx.x;
    const int wv = tid >> 6, lane = tid & 63;
    const int wr = wv >> 2, wc = wv & 3;
    const int l15 = lane & 15, l4 = lane >> 4;
    const int row0 = bx * 128;
    const _Float16* Bt = mat ? Btr : Btl;
    const float* bias  = mat ? br  : bl;
    _Float16* C        = mat ? Cr  : Cl;

    const int sr = tid >> 2;            // 0..127
    const int sk = (tid & 3) * 8;       // k offset (halves)
    const _Float16* gA  = A  + (size_t)min(row0 + sr, M - 1) * Kp + sk;
    const _Float16* gB0 = Bt + (size_t)sr * Kp + sk;
    const _Float16* gB1 = Bt + (size_t)(sr + 128) * Kp + sk;
    _Float16* lA  = &As[(wv * 16) * 32];            // wave-uniform base
    _Float16* lB0 = &Bs[(wv * 16) * 32];
    _Float16* lB1 = &Bs[(wv * 16 + 128) * 32];

    f32x4 acc[4][4];
    #pragma unroll
    for (int a = 0; a < 4; a++)
        #pragma unroll
        for (int b = 0; b < 4; b++)
            acc[a][b] = (f32x4){0.f, 0.f, 0.f, 0.f};

    for (int k0 = 0; k0 < Kp; k0 += 32) {
        GLD16(gA + k0, lA);
        GLD16(gB0 + k0, lB0);
        GLD16(gB1 + k0, lB1);
        __syncthreads();
        f16x8 wf[4], xf[4];
        #pragma unroll
        for (int ct = 0; ct < 4; ct++)
            wf[ct] = *(const f16x8*)&Bs[(wc * 64 + ct * 16 + l15) * 32 + l4 * 8];
        #pragma unroll
        for (int nt = 0; nt < 4; nt++)
            xf[nt] = *(const f16x8*)&As[(wr * 64 + nt * 16 + l15) * 32 + l4 * 8];
        #pragma unroll
        for (int ct = 0; ct < 4; ct++)
            #pragma unroll
            for (int nt = 0; nt < 4; nt++)
                acc[ct][nt] = __builtin_amdgcn_mfma_f32_16x16x32_f16(
                    wf[ct], xf[nt], acc[ct][nt], 0, 0, 0);
        __syncthreads();
    }

    float4 bv[4];
    #pragma unroll
    for (int ct = 0; ct < 4; ct++)
        bv[ct] = *(const float4*)&bias[wc * 64 + ct * 16 + l4 * 4];
    #pragma unroll
    for (int nt = 0; nt < 4; nt++) {
        int node = row0 + wr * 64 + nt * 16 + l15;
        if (node < M) {
            #pragma unroll
            for (int ct = 0; ct < 4; ct++) {
                h4 hv = {(_Float16)(acc[ct][nt][0] + bv[ct].x),
                         (_Float16)(acc[ct][nt][1] + bv[ct].y),
                         (_Float16)(acc[ct][nt][2] + bv[ct].z),
                         (_Float16)(acc[ct][nt][3] + bv[ct].w)};
                *(h4*)&C[(size_t)node * 256 + wc * 64 + ct * 16 + l4 * 4] = hv;
            }
        }
    }
}

// ---------------- Layer 3 transform via MFMA ----------------

__global__ __launch_bounds__(256) void k_gemm3_mfma(
        const _Float16* __restrict__ h,
        const _Float16* __restrict__ W3t,
        const float* __restrict__ bl, const float* __restrict__ br,
        _Float16* __restrict__ l3, int N) {
    const int wave = threadIdx.x >> 6, lane = threadIdx.x & 63;
    const int l15 = lane & 15, l4 = lane >> 4;
    const int row0 = blockIdx.x * 64 + wave * 16;
    if (row0 >= N) return;

    f16x8 bfr[8];
    #pragma unroll
    for (int ks = 0; ks < 8; ks++)
        bfr[ks] = *(const f16x8*)&W3t[l15 * 256 + ks * 32 + l4 * 8];

    const int arow = min(row0 + l15, N - 1);
    const size_t abase = (size_t)arow * 256;
    f32x4 acc = (f32x4){0.f, 0.f, 0.f, 0.f};
    #pragma unroll
    for (int ks = 0; ks < 8; ks++) {
        f16x8 af = *(const f16x8*)&h[abase + ks * 32 + l4 * 8];
        acc = __builtin_amdgcn_mfma_f32_16x16x32_f16(af, bfr[ks], acc, 0, 0, 0);
    }
    const float bv = (l15 < 6) ? bl[l15] : ((l15 < 12) ? br[l15 - 6] : 0.0f);
    #pragma unroll
    for (int r = 0; r < 4; r++) {
        int gr = row0 + l4 * 4 + r;
        if (gr < N && l15 < 12)
            l3[(size_t)gr * 16 + l15] = (_Float16)(acc[r] + bv);
    }
}

// ---------------- Aggregation layers 1&2 (H=4, C=64), fp16, online softmax ----------------
// R12 version (best measured: 49.6us, VGPR 44): 4 ch/lane; unmasked full 8-edge
// batches with 1-batch prefetch; tail preload issued first; batched tail compute.

__global__ __launch_bounds__(256) void k_agg256(const _Float16* __restrict__ xl,
                                                const _Float16* __restrict__ xr,
                                                const int* __restrict__ row_ptr,
                                                const int* __restrict__ src_sorted,
                                                const float* __restrict__ att,
                                                const float* __restrict__ bias,
                                                _Float16* __restrict__ h_out, int N) {
    const int wave = threadIdx.x >> 6;
    const int lane = threadIdx.x & 63;
    const int n = __builtin_amdgcn_readfirstlane(blockIdx.x * 4 + wave);
    if (n >= N) return;
    const int ci = lane * 4;
    const h4 xr4 = *(const h4*)&xr[(size_t)n * 256 + ci];
    const float4 at4 = *(const float4*)&att[ci];
    const h2 ata = {(_Float16)(at4.x * LOG2E), (_Float16)(at4.y * LOG2E)};
    const h2 atb = {(_Float16)(at4.z * LOG2E), (_Float16)(at4.w * LOG2E)};
    float a0 = 0.f, a1 = 0.f, a2 = 0.f, a3 = 0.f;
    float m = -INFINITY, s = 0.0f;
    const int beg = row_ptr[n], end = row_ptr[n + 1];
    const int rem = (end - beg) & 7;
    const int tb  = end - rem;

    // tail preload — issued before everything else, guarded so no extra traffic
    h4 vt[7];
    #pragma unroll
    for (int e = 0; e < 7; e++) {
        if (e < rem) {
            int sv = src_sorted[tb + e];              // uniform -> s_load
            vt[e] = *(const h4*)&xl[(size_t)sv * 256 + ci];
        }
    }

    int j = beg;
    h4 v[8], vn[8];
    bool has = (j + 8 <= tb);
    if (has) {
        #pragma unroll
        for (int e = 0; e < 8; e++) {
            int sv = src_sorted[j + e];
            v[e] = *(const h4*)&xl[(size_t)sv * 256 + ci];
        }
    }
    while (has) {
        const int jn = j + 8;
        const bool hasN = (jn + 8 <= tb);
        if (hasN) {
            #pragma unroll
            for (int e = 0; e < 8; e++) {
                int sv = src_sorted[jn + e];
                vn[e] = *(const h4*)&xl[(size_t)sv * 256 + ci];
            }
        }
        float lg[8];
        #pragma unroll
        for (int e = 0; e < 8; e++) {
            h4 t = v[e] + xr4;
            h4 lk = __builtin_elementwise_max(t, t * (_Float16)NEG_SLOPE);
            h2 lo = __builtin_shufflevector(lk, lk, 0, 1);
            h2 hi = __builtin_shufflevector(lk, lk, 2, 3);
            lg[e] = __builtin_amdgcn_fdot2(lo, ata,
                        __builtin_amdgcn_fdot2(hi, atb, 0.0f, false), false);
        }
        #pragma unroll
        for (int e = 0; e < 8; e++) lg[e] = rowsum16(lg[e]);
        float bm = fmaxf(fmaxf(fmaxf(lg[0], lg[1]), fmaxf(lg[2], lg[3])),
                         fmaxf(fmaxf(lg[4], lg[5]), fmaxf(lg[6], lg[7])));
        float nm = fmaxf(m, bm);
        float sc = __builtin_amdgcn_exp2f(m - nm);
        a0 *= sc; a1 *= sc; a2 *= sc; a3 *= sc;
        float ps = 0.f;
        #pragma unroll
        for (int e = 0; e < 8; e++) {
            float p = __builtin_amdgcn_exp2f(lg[e] - nm);
            ps += p;
            a0 = fmaf(p, (float)v[e].x, a0);
            a1 = fmaf(p, (float)v[e].y, a1);
            a2 = fmaf(p, (float)v[e].z, a2);
            a3 = fmaf(p, (float)v[e].w, a3);
        }
        s = s * sc + ps;
        m = nm;
        if (hasN) {
            #pragma unroll
            for (int e = 0; e < 8; e++) v[e] = vn[e];
        }
        j = jn;
        has = hasN;
    }

    // batched tail: rem independent logits, ONE rescale+accumulate pass
    if (rem) {
        float lg[7];
        #pragma unroll
        for (int e = 0; e < 7; e++) {
            if (e < rem) {
                h4 t = vt[e] + xr4;
                h4 lk = __builtin_elementwise_max(t, t * (_Float16)NEG_SLOPE);
                h2 lo = __builtin_shufflevector(lk, lk, 0, 1);
                h2 hi = __builtin_shufflevector(lk, lk, 2, 3);
                float d = __builtin_amdgcn_fdot2(lo, ata,
                              __builtin_amdgcn_fdot2(hi, atb, 0.0f, false), false);
                lg[e] = rowsum16(d);
            }
        }
        float bm = -INFINITY;
        #pragma unroll
        for (int e = 0; e < 7; e++)
            if (e < rem) bm = fmaxf(bm, lg[e]);
        float nm = fmaxf(m, bm);
        float sc = __builtin_amdgcn_exp2f(m - nm);
        a0 *= sc; a1 *= sc; a2 *= sc; a3 *= sc;
        float ps = 0.f;
        #pragma unroll
        for (int e = 0; e < 7; e++) {
            if (e < rem) {
                float p = __builtin_amdgcn_exp2f(lg[e] - nm);
                ps += p;
                a0 = fmaf(p, (float)vt[e].x, a0);
                a1 = fmaf(p, (float)vt[e].y, a1);
                a2 = fmaf(p, (float)vt[e].z, a2);
                a3 = fmaf(p, (float)vt[e].w, a3);
            }
        }
        s = s * sc + ps;
        m = nm;
    }

    const float inv = 1.0f / s;
    const float4 bv = *(const float4*)&bias[ci];
    float o0 = a0 * inv + bv.x;
    float o1 = a1 * inv + bv.y;
    float o2 = a2 * inv + bv.z;
    float o3 = a3 * inv + bv.w;
    o0 = o0 > 0.f ? o0 : (__expf(o0) - 1.f);
    o1 = o1 > 0.f ? o1 : (__expf(o1) - 1.f);
    o2 = o2 > 0.f ? o2 : (__expf(o2) - 1.f);
    o3 = o3 > 0.f ? o3 : (__expf(o3) - 1.f);
    h4 hv = {(_Float16)o0, (_Float16)o1, (_Float16)o2, (_Float16)o3};
    *(h4*)&h_out[(size_t)n * 256 + ci] = hv;
}

// ---------------- Layer 3 aggregation (H=6, C=1, mean over heads) ----------------

__global__ __launch_bounds__(256) void k_agg3(const _Float16* __restrict__ l3,
                                              const int* __restrict__ row_ptr,
                                              const int* __restrict__ src_sorted,
                                              const float* __restrict__ att3,
                                              const float* __restrict__ bias3,
                                              float* __restrict__ out, int N) {
    int n = blockIdx.x * 256 + threadIdx.x;
    if (n >= N) return;
    const h4* pn = (const h4*)&l3[(size_t)n * 16];
    h4 q1 = pn[1], q2 = pn[2];
    float xrv[6];
    xrv[0] = (float)q1.z; xrv[1] = (float)q1.w;
    xrv[2] = (float)q2.x; xrv[3] = (float)q2.y;
    xrv[4] = (float)q2.z; xrv[5] = (float)q2.w;
    float attv[6], m[6], s[6], acc[6];
    #pragma unroll
    for (int k = 0; k < 6; k++) {
        attv[k] = att3[k] * LOG2E;
        m[k] = -INFINITY; s[k] = 0.0f; acc[k] = 0.0f;
    }
    const int beg = row_ptr[n], end = row_ptr[n + 1];
    for (int j = beg; j < end; j += 8) {
        f16x8 u[8];
        #pragma unroll
        for (int e = 0; e < 8; e++) {
            int idx = j + e;
            idx = idx < end ? idx : end - 1;
            int sv = src_sorted[idx];
            u[e] = *(const f16x8*)&l3[(size_t)sv * 16];
        }
        #pragma unroll
        for (int e = 0; e < 8; e++) {
            const bool valid = (j + e) < end;
            float xlv[6];
            #pragma unroll
            for (int k = 0; k < 6; k++) xlv[k] = (float)u[e][k];
            #pragma unroll
            for (int k = 0; k < 6; k++) {
                float tt = xlv[k] + xrv[k];
                float lr = fmaxf(tt, NEG_SLOPE * tt);
                float logit = valid ? (attv[k] * lr) : -INFINITY;
                float nm = fmaxf(m[k], logit);
                float sc = __builtin_amdgcn_exp2f(m[k] - nm);
                float p  = __builtin_amdgcn_exp2f(logit - nm);
                acc[k] = acc[k] * sc + p * xlv[k];
                s[k]   = s[k] * sc + p;
                m[k]   = nm;
            }
        }
    }
    float o = 0.0f;
    #pragma unroll
    for (int k = 0; k < 6; k++) o += acc[k] / s[k];
    out[n] = o * (1.0f / 6.0f) + bias3[0];
}

// ---------------- launch ----------------

extern "C" void kernel_launch(void* const* d_in, const int* in_sizes, int n_in,
                              void* d_out, int out_size, void* d_ws, size_t ws_size,
                              hipStream_t stream) {
    const float* x    = (const float*)d_in[0];
    const int*   ei   = (const int*)  d_in[1];
    const float* Wl1  = (const float*)d_in[2];
    const float* bl1  = (const float*)d_in[3];
    const float* Wr1  = (const float*)d_in[4];
    const float* br1  = (const float*)d_in[5];
    const float* att1 = (const float*)d_in[6];
    const float* bias1= (const float*)d_in[7];
    const float* Wl2  = (const float*)d_in[8];
    const float* bl2  = (const float*)d_in[9];
    const float* Wr2  = (const float*)d_in[10];
    const float* br2  = (const float*)d_in[11];
    const float* att2 = (const float*)d_in[12];
    const float* bias2= (const float*)d_in[13];
    const float* Wl3  = (const float*)d_in[14];
    const float* bl3  = (const float*)d_in[15];
    const float* Wr3  = (const float*)d_in[16];
    const float* br3  = (const float*)d_in[17];
    const float* att3 = (const float*)d_in[18];
    const float* bias3= (const float*)d_in[19];

    const int F  = in_sizes[2] / 256;   // 58
    const int N  = in_sizes[0] / F;     // 50000
    const int E  = in_sizes[1] / 2;     // 500000
    const int Et = E + N;

    char* ws = (char*)d_ws;
    size_t off = 0;
    auto carve = [&](size_t bytes) -> char* {
        char* p = ws + off;
        off = (off + bytes + 255) & ~(size_t)255;
        return p;
    };
    _Float16* xb   = (_Float16*)carve((size_t)N * 64 * 2);
    _Float16* xlb  = (_Float16*)carve((size_t)N * 256 * 2);
    _Float16* xrb  = (_Float16*)carve((size_t)N * 256 * 2);
    _Float16* hb   = (_Float16*)carve((size_t)N * 256 * 2);
    _Float16* wtl1 = (_Float16*)carve(256 * 64 * 2);
    _Float16* wtr1 = (_Float16*)carve(256 * 64 * 2);
    _Float16* wtl2 = (_Float16*)carve(256 * 256 * 2);
    _Float16* wtr2 = (_Float16*)carve(256 * 256 * 2);
    _Float16* w3t  = (_Float16*)carve(16 * 256 * 2);
    _Float16* l3   = (_Float16*)carve((size_t)N * 16 * 2);
    int* cnt        = (int*)carve((size_t)N * 4);
    int* row_ptr    = (int*)carve((size_t)(N + 1) * 4);
    int* rank       = (int*)carve((size_t)Et * 4);
    int* src_sorted = (int*)carve((size_t)Et * 4);
    int* bsums      = (int*)carve(1024 * 4);

    const int gN  = (N + 255) / 256;
    const int gEt = (Et + 255) / 256;
    const int gX  = ((N << 6) + 255) / 256;
    const int gW  = (N + 3) / 4;
    const int gx1 = (N + 127) / 128;          // gemm row-blocks
    const int sB  = (Et + 511) / 512;         // scatter blocks (512 threads)

    // --- fused prep (count+rank + casts) after zeroing cnt ---
    hipMemsetAsync(cnt, 0, (size_t)N * 4, stream);
    k_prep<<<gEt + gX + 656, 256, 0, stream>>>(ei, E, Et, cnt, rank, x, xb, N, F,
                                               Wl1, Wr1, Wl2, Wr2, Wl3, Wr3,
                                               wtl1, wtr1, wtl2, wtr2, w3t, gEt, gX);

    // --- CSR scan ---
    k_scan_block<<<gN, 256, 0, stream>>>(cnt, row_ptr, bsums, N);
    k_scan_add<<<gN, 256, 0, stream>>>(row_ptr, bsums, N, Et, gN);

    // --- Layer 1 (atomic-free scatter fused: blocks [0,sB) scatter) ---
    k_gemm_pair_mfma<<<sB + 2 * gx1, 512, 0, stream>>>(
        xb, N, 64, wtl1, wtr1, bl1, br1, xlb, xrb,
        ei, E, Et, row_ptr, rank, src_sorted, sB, gx1);
    k_agg256<<<gW, 256, 0, stream>>>(xlb, xrb, row_ptr, src_sorted, att1, bias1, hb, N);

    // --- Layer 2 ---
    k_gemm_pair_mfma<<<2 * gx1, 512, 0, stream>>>(
        hb, N, 256, wtl2, wtr2, bl2, br2, xlb, xrb,
        ei, E, Et, row_ptr, rank, src_sorted, 0, gx1);
    k_agg256<<<gW, 256, 0, stream>>>(xlb, xrb, row_ptr, src_sorted, att2, bias2, hb, N);

    // --- Layer 3 ---
    k_gemm3_mfma<<<(N + 63) / 64, 256, 0, stream>>>(hb, w3t, bl3, br3, l3, N);
    k_agg3<<<(N + 255) / 256, 256, 0, stream>>>(l3, row_ptr, src_sorted, att3, bias3,
                                                (float*)d_out, N);
}

// Round 7
// 296.754 us; speedup vs baseline: 1.1308x; 1.0442x over previous
//
#include <hip/hip_runtime.h>
#include <math.h>

#define NEG_SLOPE 0.2f
#define LOG2E 1.4426950408889634f

typedef __attribute__((ext_vector_type(2))) _Float16 h2;
typedef __attribute__((ext_vector_type(4))) _Float16 h4;
typedef __attribute__((ext_vector_type(8))) _Float16 f16x8;
typedef __attribute__((ext_vector_type(4))) float f32x4;

typedef const __attribute__((address_space(1))) unsigned int* gu32p;
typedef __attribute__((address_space(3))) unsigned int* lu32p;

#define GLD16(g, l) __builtin_amdgcn_global_load_lds((gu32p)(g), (lu32p)(l), 16, 0, 0)

template<int CTRL>
__device__ __forceinline__ float dpp_add_f32(float x) {
    int y = __builtin_amdgcn_update_dpp(0, __float_as_int(x), CTRL, 0xF, 0xF, true);
    return x + __int_as_float(y);
}
__device__ __forceinline__ float rowsum16(float x) {
    x = dpp_add_f32<0xB1>(x);
    x = dpp_add_f32<0x4E>(x);
    x = dpp_add_f32<0x124>(x);
    x = dpp_add_f32<0x128>(x);
    return x;
}

// ---------------- CSR build ----------------

__global__ __launch_bounds__(256) void k_scan_block(const int* __restrict__ cnt,
                                                    int* __restrict__ out,
                                                    int* __restrict__ bsums, int n) {
    __shared__ int tmp[256];
    int t = threadIdx.x;
    int i = blockIdx.x * 256 + t;
    int v = (i < n) ? cnt[i] : 0;
    tmp[t] = v;
    __syncthreads();
    for (int d = 1; d < 256; d <<= 1) {
        int add = (t >= d) ? tmp[t - d] : 0;
        __syncthreads();
        tmp[t] += add;
        __syncthreads();
    }
    if (i < n) out[i] = tmp[t] - v;
    if (t == 255) bsums[blockIdx.x] = tmp[t];
}

// absorbs the bsums scan (nb <= 256) — one fewer launch (R13, kept: measured win).
__global__ __launch_bounds__(256) void k_scan_add(int* __restrict__ out,
                                                  const int* __restrict__ bsums,
                                                  int n, int total, int nb) {
    __shared__ int tmp[256];
    int t = threadIdx.x;
    int v = (t < nb) ? bsums[t] : 0;
    tmp[t] = v;
    __syncthreads();
    for (int d = 1; d < 256; d <<= 1) {
        int add = (t >= d) ? tmp[t - d] : 0;
        __syncthreads();
        tmp[t] += add;
        __syncthreads();
    }
    int boff = tmp[blockIdx.x] - bsums[blockIdx.x];   // exclusive prefix of block sums
    int i = blockIdx.x * 256 + t;
    if (i < n) out[i] += boff;
    if (i == 0) out[n] = total;
}

// ---------------- fused prep: edge count+rank + x cast + all weight casts ----------------
// R16 (kept): the counting atomicAdd's return value IS the in-bucket rank — store it.
// The scatter then needs no atomics at all (pos = row_ptr[d] + rank[e]).

__global__ __launch_bounds__(256) void k_prep(
        const int* __restrict__ ei, int E, int Et, int* __restrict__ cnt,
        int* __restrict__ rank,
        const float* __restrict__ x, _Float16* __restrict__ xb, int N, int F,
        const float* __restrict__ Wl1, const float* __restrict__ Wr1,
        const float* __restrict__ Wl2, const float* __restrict__ Wr2,
        const float* __restrict__ Wl3, const float* __restrict__ Wr3,
        _Float16* __restrict__ wtl1, _Float16* __restrict__ wtr1,
        _Float16* __restrict__ wtl2, _Float16* __restrict__ wtr2,
        _Float16* __restrict__ w3t, int gEt, int gX) {
    const int b = blockIdx.x;
    if (b < gEt) {
        int e = b * 256 + threadIdx.x;
        if (e < Et) {
            int d = (e < E) ? ei[E + e] : (e - E);
            rank[e] = atomicAdd(&cnt[d], 1);
        }
    } else if (b < gEt + gX) {
        int i = (b - gEt) * 256 + threadIdx.x;
        if (i < (N << 6)) {
            int n = i >> 6, k = i & 63;
            xb[i] = (_Float16)(k < F ? x[n * F + k] : 0.0f);
        }
    } else {
        int i = (b - gEt - gX) * 256 + threadIdx.x;
        if (i < 32768) {
            const float* W = (i < 16384) ? Wl1 : Wr1;
            _Float16* O = (i < 16384) ? wtl1 : wtr1;
            int loc = i & 16383;
            int n = loc >> 6, k = loc & 63;
            O[loc] = (_Float16)(k < F ? W[k * 256 + n] : 0.0f);
        } else if (i < 163840) {
            int seg = i - 32768;
            const float* W = (seg < 65536) ? Wl2 : Wr2;
            _Float16* O = (seg < 65536) ? wtl2 : wtr2;
            int loc = seg & 65535;
            int n = loc >> 8, k = loc & 255;
            O[loc] = (_Float16)W[k * 256 + n];
        } else if (i < 167936) {
            int loc = i - 163840;
            int j = loc >> 8, k = loc & 255;
            float v = (j < 6) ? Wl3[k * 6 + j] : ((j < 12) ? Wr3[k * 6 + (j - 6)] : 0.0f);
            w3t[loc] = (_Float16)v;
        }
    }
}

// ---------------- MFMA fp16 GEMM pair (+ fused atomic-free edge scatter) ----------------
// 512-thread blocks, 128 rows x 256 cols per block. Blocks [0,sB) do the scatter:
// pure load->store (rank precomputed in k_prep). K-step kept at 32: K-step 64 would
// double LDS to 48KB and halve resident blocks — the documented m132 regression mode.

__global__ __launch_bounds__(512) void k_gemm_pair_mfma(
        const _Float16* __restrict__ A, int M, int Kp,
        const _Float16* __restrict__ Btl, const _Float16* __restrict__ Btr,
        const float* __restrict__ bl, const float* __restrict__ br,
        _Float16* __restrict__ Cl, _Float16* __restrict__ Cr,
        const int* __restrict__ ei, int E, int Et,
        const int* __restrict__ row_ptr, const int* __restrict__ rank,
        int* __restrict__ src_sorted,
        int sB, int gX) {
    __shared__ _Float16 As[128 * 32];
    __shared__ _Float16 Bs[256 * 32];
    if (blockIdx.x < sB) {
        int e = blockIdx.x * 512 + threadIdx.x;
        if (e < Et) {
            int s, d;
            if (e < E) { s = ei[e]; d = ei[E + e]; } else { s = d = e - E; }
            src_sorted[row_ptr[d] + rank[e]] = s;
        }
        return;
    }
    const int gb = blockIdx.x - sB;
    const int mat = gb >= gX;
    const int bx  = mat ? gb - gX : gb;
    const int tid = threadIdx.x;
    const int wv = tid >> 6, lane = tid & 63;
    const int wr = wv >> 2, wc = wv & 3;
    const int l15 = lane & 15, l4 = lane >> 4;
    const int row0 = bx * 128;
    const _Float16* Bt = mat ? Btr : Btl;
    const float* bias  = mat ? br  : bl;
    _Float16* C        = mat ? Cr  : Cl;

    const int sr = tid >> 2;            // 0..127
    const int sk = (tid & 3) * 8;       // k offset (halves)
    const _Float16* gA  = A  + (size_t)min(row0 + sr, M - 1) * Kp + sk;
    const _Float16* gB0 = Bt + (size_t)sr * Kp + sk;
    const _Float16* gB1 = Bt + (size_t)(sr + 128) * Kp + sk;
    _Float16* lA  = &As[(wv * 16) * 32];            // wave-uniform base
    _Float16* lB0 = &Bs[(wv * 16) * 32];
    _Float16* lB1 = &Bs[(wv * 16 + 128) * 32];

    f32x4 acc[4][4];
    #pragma unroll
    for (int a = 0; a < 4; a++)
        #pragma unroll
        for (int b = 0; b < 4; b++)
            acc[a][b] = (f32x4){0.f, 0.f, 0.f, 0.f};

    for (int k0 = 0; k0 < Kp; k0 += 32) {
        GLD16(gA + k0, lA);
        GLD16(gB0 + k0, lB0);
        GLD16(gB1 + k0, lB1);
        __syncthreads();
        f16x8 wf[4], xf[4];
        #pragma unroll
        for (int ct = 0; ct < 4; ct++)
            wf[ct] = *(const f16x8*)&Bs[(wc * 64 + ct * 16 + l15) * 32 + l4 * 8];
        #pragma unroll
        for (int nt = 0; nt < 4; nt++)
            xf[nt] = *(const f16x8*)&As[(wr * 64 + nt * 16 + l15) * 32 + l4 * 8];
        #pragma unroll
        for (int ct = 0; ct < 4; ct++)
            #pragma unroll
            for (int nt = 0; nt < 4; nt++)
                acc[ct][nt] = __builtin_amdgcn_mfma_f32_16x16x32_f16(
                    wf[ct], xf[nt], acc[ct][nt], 0, 0, 0);
        __syncthreads();
    }

    float4 bv[4];
    #pragma unroll
    for (int ct = 0; ct < 4; ct++)
        bv[ct] = *(const float4*)&bias[wc * 64 + ct * 16 + l4 * 4];
    #pragma unroll
    for (int nt = 0; nt < 4; nt++) {
        int node = row0 + wr * 64 + nt * 16 + l15;
        if (node < M) {
            #pragma unroll
            for (int ct = 0; ct < 4; ct++) {
                h4 hv = {(_Float16)(acc[ct][nt][0] + bv[ct].x),
                         (_Float16)(acc[ct][nt][1] + bv[ct].y),
                         (_Float16)(acc[ct][nt][2] + bv[ct].z),
                         (_Float16)(acc[ct][nt][3] + bv[ct].w)};
                *(h4*)&C[(size_t)node * 256 + wc * 64 + ct * 16 + l4 * 4] = hv;
            }
        }
    }
}

// ---------------- Layer 3 transform via MFMA ----------------

__global__ __launch_bounds__(256) void k_gemm3_mfma(
        const _Float16* __restrict__ h,
        const _Float16* __restrict__ W3t,
        const float* __restrict__ bl, const float* __restrict__ br,
        _Float16* __restrict__ l3, int N) {
    const int wave = threadIdx.x >> 6, lane = threadIdx.x & 63;
    const int l15 = lane & 15, l4 = lane >> 4;
    const int row0 = blockIdx.x * 64 + wave * 16;
    if (row0 >= N) return;

    f16x8 bfr[8];
    #pragma unroll
    for (int ks = 0; ks < 8; ks++)
        bfr[ks] = *(const f16x8*)&W3t[l15 * 256 + ks * 32 + l4 * 8];

    const int arow = min(row0 + l15, N - 1);
    const size_t abase = (size_t)arow * 256;
    f32x4 acc = (f32x4){0.f, 0.f, 0.f, 0.f};
    #pragma unroll
    for (int ks = 0; ks < 8; ks++) {
        f16x8 af = *(const f16x8*)&h[abase + ks * 32 + l4 * 8];
        acc = __builtin_amdgcn_mfma_f32_16x16x32_f16(af, bfr[ks], acc, 0, 0, 0);
    }
    const float bv = (l15 < 6) ? bl[l15] : ((l15 < 12) ? br[l15 - 6] : 0.0f);
    #pragma unroll
    for (int r = 0; r < 4; r++) {
        int gr = row0 + l4 * 4 + r;
        if (gr < N && l15 < 12)
            l3[(size_t)gr * 16 + l15] = (_Float16)(acc[r] + bv);
    }
}

// ---------------- Aggregation layers 1&2 (H=4, C=64), fp16, online softmax ----------------
// R12 structure (validated): 4 ch/lane; unmasked full 8-edge batches with 1-batch
// prefetch; tail preload issued first; batched tail compute with ONE rescale pass.
// R17: accumulator in packed fp16 (v_pk_fma_f16): removes 4 cvt + 4 f32 fma per edge,
// same dataflow/order. Precision: ~1e-3 rel on O(3) values vs 1.67e-2 threshold.

__global__ __launch_bounds__(256) void k_agg256(const _Float16* __restrict__ xl,
                                                const _Float16* __restrict__ xr,
                                                const int* __restrict__ row_ptr,
                                                const int* __restrict__ src_sorted,
                                                const float* __restrict__ att,
                                                const float* __restrict__ bias,
                                                _Float16* __restrict__ h_out, int N) {
    const int wave = threadIdx.x >> 6;
    const int lane = threadIdx.x & 63;
    const int n = __builtin_amdgcn_readfirstlane(blockIdx.x * 4 + wave);
    if (n >= N) return;
    const int ci = lane * 4;
    const h4 xr4 = *(const h4*)&xr[(size_t)n * 256 + ci];
    const float4 at4 = *(const float4*)&att[ci];
    const h2 ata = {(_Float16)(at4.x * LOG2E), (_Float16)(at4.y * LOG2E)};
    const h2 atb = {(_Float16)(at4.z * LOG2E), (_Float16)(at4.w * LOG2E)};
    h4 a4 = {(_Float16)0.f, (_Float16)0.f, (_Float16)0.f, (_Float16)0.f};
    float m = -INFINITY, s = 0.0f;
    const int beg = row_ptr[n], end = row_ptr[n + 1];
    const int rem = (end - beg) & 7;
    const int tb  = end - rem;

    // tail preload — issued before everything else, guarded so no extra traffic
    h4 vt[7];
    #pragma unroll
    for (int e = 0; e < 7; e++) {
        if (e < rem) {
            int sv = src_sorted[tb + e];              // uniform -> s_load
            vt[e] = *(const h4*)&xl[(size_t)sv * 256 + ci];
        }
    }

    int j = beg;
    h4 v[8], vn[8];
    bool has = (j + 8 <= tb);
    if (has) {
        #pragma unroll
        for (int e = 0; e < 8; e++) {
            int sv = src_sorted[j + e];
            v[e] = *(const h4*)&xl[(size_t)sv * 256 + ci];
        }
    }
    while (has) {
        const int jn = j + 8;
        const bool hasN = (jn + 8 <= tb);
        if (hasN) {
            #pragma unroll
            for (int e = 0; e < 8; e++) {
                int sv = src_sorted[jn + e];
                vn[e] = *(const h4*)&xl[(size_t)sv * 256 + ci];
            }
        }
        float lg[8];
        #pragma unroll
        for (int e = 0; e < 8; e++) {
            h4 t = v[e] + xr4;
            h4 lk = __builtin_elementwise_max(t, t * (_Float16)NEG_SLOPE);
            h2 lo = __builtin_shufflevector(lk, lk, 0, 1);
            h2 hi = __builtin_shufflevector(lk, lk, 2, 3);
            lg[e] = __builtin_amdgcn_fdot2(lo, ata,
                        __builtin_amdgcn_fdot2(hi, atb, 0.0f, false), false);
        }
        #pragma unroll
        for (int e = 0; e < 8; e++) lg[e] = rowsum16(lg[e]);
        float bm = fmaxf(fmaxf(fmaxf(lg[0], lg[1]), fmaxf(lg[2], lg[3])),
                         fmaxf(fmaxf(lg[4], lg[5]), fmaxf(lg[6], lg[7])));
        float nm = fmaxf(m, bm);
        float sc = __builtin_amdgcn_exp2f(m - nm);
        {
            _Float16 sc16 = (_Float16)sc;
            a4 *= (h4){sc16, sc16, sc16, sc16};
        }
        float ps = 0.f;
        #pragma unroll
        for (int e = 0; e < 8; e++) {
            float p = __builtin_amdgcn_exp2f(lg[e] - nm);
            ps += p;
            _Float16 p16 = (_Float16)p;
            a4 = __builtin_elementwise_fma((h4){p16, p16, p16, p16}, v[e], a4);
        }
        s = s * sc + ps;
        m = nm;
        if (hasN) {
            #pragma unroll
            for (int e = 0; e < 8; e++) v[e] = vn[e];
        }
        j = jn;
        has = hasN;
    }

    // batched tail: rem independent logits, ONE rescale+accumulate pass
    if (rem) {
        float lg[7];
        #pragma unroll
        for (int e = 0; e < 7; e++) {
            if (e < rem) {
                h4 t = vt[e] + xr4;
                h4 lk = __builtin_elementwise_max(t, t * (_Float16)NEG_SLOPE);
                h2 lo = __builtin_shufflevector(lk, lk, 0, 1);
                h2 hi = __builtin_shufflevector(lk, lk, 2, 3);
                float d = __builtin_amdgcn_fdot2(lo, ata,
                              __builtin_amdgcn_fdot2(hi, atb, 0.0f, false), false);
                lg[e] = rowsum16(d);
            }
        }
        float bm = -INFINITY;
        #pragma unroll
        for (int e = 0; e < 7; e++)
            if (e < rem) bm = fmaxf(bm, lg[e]);
        float nm = fmaxf(m, bm);
        float sc = __builtin_amdgcn_exp2f(m - nm);
        {
            _Float16 sc16 = (_Float16)sc;
            a4 *= (h4){sc16, sc16, sc16, sc16};
        }
        float ps = 0.f;
        #pragma unroll
        for (int e = 0; e < 7; e++) {
            if (e < rem) {
                float p = __builtin_amdgcn_exp2f(lg[e] - nm);
                ps += p;
                _Float16 p16 = (_Float16)p;
                a4 = __builtin_elementwise_fma((h4){p16, p16, p16, p16}, vt[e], a4);
            }
        }
        s = s * sc + ps;
        m = nm;
    }

    const float inv = 1.0f / s;
    const float4 bv = *(const float4*)&bias[ci];
    float o0 = (float)a4.x * inv + bv.x;
    float o1 = (float)a4.y * inv + bv.y;
    float o2 = (float)a4.z * inv + bv.z;
    float o3 = (float)a4.w * inv + bv.w;
    o0 = o0 > 0.f ? o0 : (__expf(o0) - 1.f);
    o1 = o1 > 0.f ? o1 : (__expf(o1) - 1.f);
    o2 = o2 > 0.f ? o2 : (__expf(o2) - 1.f);
    o3 = o3 > 0.f ? o3 : (__expf(o3) - 1.f);
    h4 hv = {(_Float16)o0, (_Float16)o1, (_Float16)o2, (_Float16)o3};
    *(h4*)&h_out[(size_t)n * 256 + ci] = hv;
}

// ---------------- Layer 3 aggregation (H=6, C=1, mean over heads) ----------------
// R17: thread per (node, head) — old thread-per-node version launched only 50K
// threads (0.76 waves/SIMD, fully latency-exposed). Now 8x parallelism; lanes 0-5
// of each aligned 8-lane group handle heads, mean via 3 shfl_xor (lanes 6-7 stay
// active through the shuffles with val=0). l3 is L2-resident (1.6MB).

__global__ __launch_bounds__(256) void k_agg3(const _Float16* __restrict__ l3,
                                              const int* __restrict__ row_ptr,
                                              const int* __restrict__ src_sorted,
                                              const float* __restrict__ att3,
                                              const float* __restrict__ bias3,
                                              float* __restrict__ out, int N) {
    const int idx = blockIdx.x * 256 + threadIdx.x;
    const int n = idx >> 3, h = idx & 7;
    if (n >= N) return;                 // uniform per 8-lane group
    float val = 0.0f;
    if (h < 6) {
        const float xrv = (float)l3[(size_t)n * 16 + 6 + h];
        const float attv = att3[h] * LOG2E;
        float m = -INFINITY, s = 0.0f, acc = 0.0f;
        const int beg = row_ptr[n], end = row_ptr[n + 1];
        for (int j = beg; j < end; j += 8) {
            float xlv[8];
            #pragma unroll
            for (int e = 0; e < 8; e++) {
                int i2 = j + e; i2 = i2 < end ? i2 : end - 1;
                int sv = src_sorted[i2];
                xlv[e] = (float)l3[(size_t)sv * 16 + h];
            }
            #pragma unroll
            for (int e = 0; e < 8; e++) {
                const bool valid = (j + e) < end;
                float tt = xlv[e] + xrv;
                float lr = fmaxf(tt, NEG_SLOPE * tt);
                float logit = valid ? (attv * lr) : -INFINITY;
                float nm = fmaxf(m, logit);
                float sc = __builtin_amdgcn_exp2f(m - nm);
                float p  = __builtin_amdgcn_exp2f(logit - nm);
                acc = acc * sc + p * xlv[e];
                s   = s * sc + p;
                m   = nm;
            }
        }
        val = acc / s;
    }
    val += __shfl_xor(val, 1);
    val += __shfl_xor(val, 2);
    val += __shfl_xor(val, 4);
    if (h == 0) out[n] = val * (1.0f / 6.0f) + bias3[0];
}

// ---------------- launch ----------------

extern "C" void kernel_launch(void* const* d_in, const int* in_sizes, int n_in,
                              void* d_out, int out_size, void* d_ws, size_t ws_size,
                              hipStream_t stream) {
    const float* x    = (const float*)d_in[0];
    const int*   ei   = (const int*)  d_in[1];
    const float* Wl1  = (const float*)d_in[2];
    const float* bl1  = (const float*)d_in[3];
    const float* Wr1  = (const float*)d_in[4];
    const float* br1  = (const float*)d_in[5];
    const float* att1 = (const float*)d_in[6];
    const float* bias1= (const float*)d_in[7];
    const float* Wl2  = (const float*)d_in[8];
    const float* bl2  = (const float*)d_in[9];
    const float* Wr2  = (const float*)d_in[10];
    const float* br2  = (const float*)d_in[11];
    const float* att2 = (const float*)d_in[12];
    const float* bias2= (const float*)d_in[13];
    const float* Wl3  = (const float*)d_in[14];
    const float* bl3  = (const float*)d_in[15];
    const float* Wr3  = (const float*)d_in[16];
    const float* br3  = (const float*)d_in[17];
    const float* att3 = (const float*)d_in[18];
    const float* bias3= (const float*)d_in[19];

    const int F  = in_sizes[2] / 256;   // 58
    const int N  = in_sizes[0] / F;     // 50000
    const int E  = in_sizes[1] / 2;     // 500000
    const int Et = E + N;

    char* ws = (char*)d_ws;
    size_t off = 0;
    auto carve = [&](size_t bytes) -> char* {
        char* p = ws + off;
        off = (off + bytes + 255) & ~(size_t)255;
        return p;
    };
    _Float16* xb   = (_Float16*)carve((size_t)N * 64 * 2);
    _Float16* xlb  = (_Float16*)carve((size_t)N * 256 * 2);
    _Float16* xrb  = (_Float16*)carve((size_t)N * 256 * 2);
    _Float16* hb   = (_Float16*)carve((size_t)N * 256 * 2);
    _Float16* wtl1 = (_Float16*)carve(256 * 64 * 2);
    _Float16* wtr1 = (_Float16*)carve(256 * 64 * 2);
    _Float16* wtl2 = (_Float16*)carve(256 * 256 * 2);
    _Float16* wtr2 = (_Float16*)carve(256 * 256 * 2);
    _Float16* w3t  = (_Float16*)carve(16 * 256 * 2);
    _Float16* l3   = (_Float16*)carve((size_t)N * 16 * 2);
    int* cnt        = (int*)carve((size_t)N * 4);
    int* row_ptr    = (int*)carve((size_t)(N + 1) * 4);
    int* rank       = (int*)carve((size_t)Et * 4);
    int* src_sorted = (int*)carve((size_t)Et * 4);
    int* bsums      = (int*)carve(1024 * 4);

    const int gN  = (N + 255) / 256;
    const int gEt = (Et + 255) / 256;
    const int gX  = ((N << 6) + 255) / 256;
    const int gW  = (N + 3) / 4;
    const int gx1 = (N + 127) / 128;          // gemm row-blocks
    const int sB  = (Et + 511) / 512;         // scatter blocks (512 threads)

    // --- fused prep (count+rank + casts) after zeroing cnt ---
    hipMemsetAsync(cnt, 0, (size_t)N * 4, stream);
    k_prep<<<gEt + gX + 656, 256, 0, stream>>>(ei, E, Et, cnt, rank, x, xb, N, F,
                                               Wl1, Wr1, Wl2, Wr2, Wl3, Wr3,
                                               wtl1, wtr1, wtl2, wtr2, w3t, gEt, gX);

    // --- CSR scan ---
    k_scan_block<<<gN, 256, 0, stream>>>(cnt, row_ptr, bsums, N);
    k_scan_add<<<gN, 256, 0, stream>>>(row_ptr, bsums, N, Et, gN);

    // --- Layer 1 (atomic-free scatter fused: blocks [0,sB) scatter) ---
    k_gemm_pair_mfma<<<sB + 2 * gx1, 512, 0, stream>>>(
        xb, N, 64, wtl1, wtr1, bl1, br1, xlb, xrb,
        ei, E, Et, row_ptr, rank, src_sorted, sB, gx1);
    k_agg256<<<gW, 256, 0, stream>>>(xlb, xrb, row_ptr, src_sorted, att1, bias1, hb, N);

    // --- Layer 2 ---
    k_gemm_pair_mfma<<<2 * gx1, 512, 0, stream>>>(
        hb, N, 256, wtl2, wtr2, bl2, br2, xlb, xrb,
        ei, E, Et, row_ptr, rank, src_sorted, 0, gx1);
    k_agg256<<<gW, 256, 0, stream>>>(xlb, xrb, row_ptr, src_sorted, att2, bias2, hb, N);

    // --- Layer 3 ---
    k_gemm3_mfma<<<(N + 63) / 64, 256, 0, stream>>>(hb, w3t, bl3, br3, l3, N);
    k_agg3<<<((N * 8) + 255) / 256, 256, 0, stream>>>(l3, row_ptr, src_sorted, att3, bias3,
                                                      (float*)d_out, N);
}